// Round 1
// baseline (1712.992 us; speedup 1.0000x reference)
//
#include <hip/hip_runtime.h>
#include <math.h>

#define N_NODES 100000
#define N_EDGES 1600000
#define INDIM 128
#define F 64
#define ODIM 10
#define NG 512

// ---------------- utility ----------------
__global__ void zero_kernel(float* p, int n) {
    int i = blockIdx.x * blockDim.x + threadIdx.x;
    if (i < n) p[i] = 0.0f;
}

__global__ void deg_kernel(const int* __restrict__ dst, float* __restrict__ deg) {
    int e = blockIdx.x * blockDim.x + threadIdx.x;
    if (e < N_EDGES) atomicAdd(&deg[dst[e]], 1.0f);
}

__global__ void dinv_kernel(float* deg) {
    int i = blockIdx.x * blockDim.x + threadIdx.x;
    if (i < N_NODES) deg[i] = rsqrtf(deg[i] + 1.0f);  // +1 for self-loop
}

__global__ void cnt_kernel(const int* __restrict__ batch, float* __restrict__ cnt) {
    int i = blockIdx.x * blockDim.x + threadIdx.x;
    if (i < N_NODES) atomicAdd(&cnt[batch[i]], 1.0f);
}

// ---------------- GEMM: h = x @ W   (x: [N,K], W: [K,64]) ----------------
// 256 threads = 4 nodes x 64 cols; one wave handles one node. W staged in LDS.
template <int K>
__global__ void gemm_kernel(const float* __restrict__ x, const float* __restrict__ W,
                            float* __restrict__ h) {
    __shared__ float Wl[K * 64];
    for (int i = threadIdx.x; i < K * 64; i += 256) Wl[i] = W[i];
    __syncthreads();
    int node = blockIdx.x * 4 + (threadIdx.x >> 6);
    int col  = threadIdx.x & 63;
    float xr[K / 64];
#pragma unroll
    for (int j = 0; j < K / 64; ++j) xr[j] = x[node * K + j * 64 + col];
    float acc = 0.0f;
#pragma unroll
    for (int j = 0; j < K / 64; ++j) {
#pragma unroll 8
        for (int k = 0; k < 64; ++k) {
            float xv = __shfl(xr[j], k, 64);
            acc += xv * Wl[(j * 64 + k) * 64 + col];
        }
    }
    h[node * F + col] = acc;
}

// ---------------- out = h * dinv^2 + bias  (self-loop term + bias init) ----------------
__global__ void selfloop_bias_kernel(const float* __restrict__ h, const float* __restrict__ dinv,
                                     const float* __restrict__ b, float* __restrict__ out) {
    int idx = blockIdx.x * blockDim.x + threadIdx.x;
    int i = idx >> 6, f = idx & 63;
    if (i < N_NODES) {
        float di = dinv[i];
        out[idx] = h[idx] * di * di + b[f];
    }
}

// ---------------- edge scatter: out[dst] += h[src] * dinv[src]*dinv[dst] ----------------
// one wave (64 lanes) per edge -> coalesced 256B gather + coalesced 256B atomic add
__global__ void scatter_kernel(const int* __restrict__ src, const int* __restrict__ dst,
                               const float* __restrict__ dinv, const float* __restrict__ h,
                               float* __restrict__ out) {
    long long idx = (long long)blockIdx.x * blockDim.x + threadIdx.x;
    int e = (int)(idx >> 6);
    int f = (int)(idx & 63);
    if (e >= N_EDGES) return;
    int s = src[e], d = dst[e];
    float norm = dinv[s] * dinv[d];
    atomicAdd(&out[(long long)d * F + f], h[(long long)s * F + f] * norm);
}

// ---------------- relu in place + pooling accumulate ----------------
__global__ void relu_pool_kernel(float* __restrict__ out, const int* __restrict__ batch,
                                 float* __restrict__ sums) {
    int idx = blockIdx.x * blockDim.x + threadIdx.x;
    int i = idx >> 6, f = idx & 63;
    if (i >= N_NODES) return;
    float v = fmaxf(out[idx], 0.0f);
    out[idx] = v;
    atomicAdd(&sums[batch[i] * F + f], v);
}

// ---------------- head: gcat[g, l*10+c] = (sums_l[g]/cnt[g]) @ Wl_l + bl_l ----------------
__global__ void head_kernel(const float* __restrict__ sums, const float* __restrict__ cnt,
                            const float* __restrict__ Wl1, const float* __restrict__ bl1,
                            const float* __restrict__ Wl2, const float* __restrict__ bl2,
                            const float* __restrict__ Wl3, const float* __restrict__ bl3,
                            float* __restrict__ gcat) {
    int g = blockIdx.x;
    int t = threadIdx.x;
    if (t >= 30) return;
    int l = t / 10, c = t % 10;
    const float* Wl = (l == 0) ? Wl1 : (l == 1) ? Wl2 : Wl3;
    const float* bl = (l == 0) ? bl1 : (l == 1) ? bl2 : bl3;
    float invc = 1.0f / fmaxf(cnt[g], 1.0f);
    const float* srow = sums + (long long)l * NG * F + (long long)g * F;
    float acc = bl[c];
    for (int k = 0; k < F; ++k) acc += srow[k] * invc * Wl[k * ODIM + c];
    gcat[g * 30 + t] = acc;
}

// ---------------- final: softmax(gcat @ Wf + bf) ----------------
__global__ void final_kernel(const float* __restrict__ gcat, const float* __restrict__ Wf,
                             const float* __restrict__ bf, float* __restrict__ out) {
    int g = blockIdx.x * blockDim.x + threadIdx.x;
    if (g >= NG) return;
    float z[ODIM];
    float m = -1e30f;
    for (int c = 0; c < ODIM; ++c) {
        float acc = bf[c];
        for (int k = 0; k < 30; ++k) acc += gcat[g * 30 + k] * Wf[k * ODIM + c];
        z[c] = acc;
        m = fmaxf(m, acc);
    }
    float s = 0.0f;
    for (int c = 0; c < ODIM; ++c) { z[c] = expf(z[c] - m); s += z[c]; }
    float inv = 1.0f / s;
    for (int c = 0; c < ODIM; ++c) out[g * ODIM + c] = z[c] * inv;
}

extern "C" void kernel_launch(void* const* d_in, const int* in_sizes, int n_in,
                              void* d_out, int out_size, void* d_ws, size_t ws_size,
                              hipStream_t stream) {
    const float* features = (const float*)d_in[0];
    const int*   edge     = (const int*)d_in[1];
    const int*   batch    = (const int*)d_in[2];
    const float* W1 = (const float*)d_in[3];
    const float* b1 = (const float*)d_in[4];
    const float* W2 = (const float*)d_in[5];
    const float* b2 = (const float*)d_in[6];
    const float* W3 = (const float*)d_in[7];
    const float* b3 = (const float*)d_in[8];
    const float* Wl1 = (const float*)d_in[9];
    const float* bl1 = (const float*)d_in[10];
    const float* Wl2 = (const float*)d_in[11];
    const float* bl2 = (const float*)d_in[12];
    const float* Wl3 = (const float*)d_in[13];
    const float* bl3 = (const float*)d_in[14];
    const float* Wf = (const float*)d_in[15];
    const float* bf = (const float*)d_in[16];

    const int* src = edge;
    const int* dst = edge + N_EDGES;

    // workspace layout (floats): [dinv | sums(3*512*64) | cnt(512) | gcat | A | B | C]
    float* ws    = (float*)d_ws;
    float* dinv  = ws;
    float* sums  = dinv + N_NODES;             // 3*NG*F
    float* cnt   = sums + 3 * NG * F;          // NG
    float* gcat  = cnt + NG;                   // NG*30
    float* bufA  = gcat + NG * 30;
    float* bufB  = bufA + (long long)N_NODES * F;
    float* bufC  = bufB + (long long)N_NODES * F;

    const int zeroN = N_NODES + 3 * NG * F + NG;  // dinv..cnt contiguous
    hipLaunchKernelGGL(zero_kernel, dim3((zeroN + 255) / 256), dim3(256), 0, stream, dinv, zeroN);
    hipLaunchKernelGGL(deg_kernel, dim3((N_EDGES + 255) / 256), dim3(256), 0, stream, dst, dinv);
    hipLaunchKernelGGL(dinv_kernel, dim3((N_NODES + 255) / 256), dim3(256), 0, stream, dinv);
    hipLaunchKernelGGL(cnt_kernel, dim3((N_NODES + 255) / 256), dim3(256), 0, stream, batch, cnt);

    const int nodeBlocks = N_NODES / 4;                       // 25000 (100000 % 4 == 0)
    const int nfBlocks   = (N_NODES * F) / 256;               // 25000
    const int edgeBlocks = (int)(((long long)N_EDGES * 64) / 256);  // 400000

    // ---- layer 1: in=features(K=128), h=B, agg=A ----
    hipLaunchKernelGGL((gemm_kernel<INDIM>), dim3(nodeBlocks), dim3(256), 0, stream, features, W1, bufB);
    hipLaunchKernelGGL(selfloop_bias_kernel, dim3(nfBlocks), dim3(256), 0, stream, bufB, dinv, b1, bufA);
    hipLaunchKernelGGL(scatter_kernel, dim3(edgeBlocks), dim3(256), 0, stream, src, dst, dinv, bufB, bufA);
    hipLaunchKernelGGL(relu_pool_kernel, dim3(nfBlocks), dim3(256), 0, stream, bufA, batch, sums + 0 * NG * F);

    // ---- layer 2: in=A(K=64), h=B, agg=C ----
    hipLaunchKernelGGL((gemm_kernel<F>), dim3(nodeBlocks), dim3(256), 0, stream, bufA, W2, bufB);
    hipLaunchKernelGGL(selfloop_bias_kernel, dim3(nfBlocks), dim3(256), 0, stream, bufB, dinv, b2, bufC);
    hipLaunchKernelGGL(scatter_kernel, dim3(edgeBlocks), dim3(256), 0, stream, src, dst, dinv, bufB, bufC);
    hipLaunchKernelGGL(relu_pool_kernel, dim3(nfBlocks), dim3(256), 0, stream, bufC, batch, sums + 1 * NG * F);

    // ---- layer 3: in=C(K=64), h=B, agg=A ----
    hipLaunchKernelGGL((gemm_kernel<F>), dim3(nodeBlocks), dim3(256), 0, stream, bufC, W3, bufB);
    hipLaunchKernelGGL(selfloop_bias_kernel, dim3(nfBlocks), dim3(256), 0, stream, bufB, dinv, b3, bufA);
    hipLaunchKernelGGL(scatter_kernel, dim3(edgeBlocks), dim3(256), 0, stream, src, dst, dinv, bufB, bufA);
    hipLaunchKernelGGL(relu_pool_kernel, dim3(nfBlocks), dim3(256), 0, stream, bufA, batch, sums + 2 * NG * F);

    // ---- heads + final softmax ----
    hipLaunchKernelGGL(head_kernel, dim3(NG), dim3(32), 0, stream, sums, cnt,
                       Wl1, bl1, Wl2, bl2, Wl3, bl3, gcat);
    hipLaunchKernelGGL(final_kernel, dim3((NG + 255) / 256), dim3(256), 0, stream, gcat, Wf, bf, (float*)d_out);
}

// Round 2
// 955.345 us; speedup vs baseline: 1.7931x; 1.7931x over previous
//
#include <hip/hip_runtime.h>
#include <math.h>

#define N_NODES 100000
#define N_EDGES 1600000
#define INDIM 128
#define F 64
#define ODIM 10
#define NG 512
#define NB_SCAN ((N_NODES + 255) / 256)  // 391

// ---------------- utility ----------------
__global__ void zero_kernel(float* p, int n) {
    int i = blockIdx.x * blockDim.x + threadIdx.x;
    if (i < n) p[i] = 0.0f;
}

__global__ void deg_kernel(const int* __restrict__ dst, int* __restrict__ deg) {
    int e = blockIdx.x * blockDim.x + threadIdx.x;
    if (e < N_EDGES) atomicAdd(&deg[dst[e]], 1);
}

__global__ void dinv_kernel(const int* __restrict__ deg, float* __restrict__ dinv) {
    int i = blockIdx.x * blockDim.x + threadIdx.x;
    if (i < N_NODES) dinv[i] = rsqrtf((float)deg[i] + 1.0f);  // +1 self-loop
}

__global__ void cnt_kernel(const int* __restrict__ batch, float* __restrict__ cnt) {
    int i = blockIdx.x * blockDim.x + threadIdx.x;
    if (i < N_NODES) atomicAdd(&cnt[batch[i]], 1.0f);
}

// ---------------- CSR build: scan of degrees, then bin edges ----------------
__global__ void scan1_kernel(const int* __restrict__ deg, int* __restrict__ rp,
                             int* __restrict__ bsum) {
    int i = blockIdx.x * 256 + threadIdx.x;
    int v = (i < N_NODES) ? deg[i] : 0;
    int lane = threadIdx.x & 63, w = threadIdx.x >> 6;
    int x = v;
#pragma unroll
    for (int off = 1; off < 64; off <<= 1) {
        int y = __shfl_up(x, off, 64);
        if (lane >= off) x += y;
    }
    __shared__ int wsum[4];
    if (lane == 63) wsum[w] = x;
    __syncthreads();
    int add = 0;
    for (int j = 0; j < w; ++j) add += wsum[j];
    if (i < N_NODES) rp[i] = x - v + add;          // block-local exclusive
    if (threadIdx.x == 255) bsum[blockIdx.x] = x + add;  // block total
}

__global__ void scan2_kernel(int* __restrict__ bsum) {  // 1 block, 512 thr, in-place exclusive
    int i = threadIdx.x;
    int v = (i < NB_SCAN) ? bsum[i] : 0;
    int lane = i & 63, w = i >> 6;
    int x = v;
#pragma unroll
    for (int off = 1; off < 64; off <<= 1) {
        int y = __shfl_up(x, off, 64);
        if (lane >= off) x += y;
    }
    __shared__ int wsum[8];
    if (lane == 63) wsum[w] = x;
    __syncthreads();
    int add = 0;
    for (int j = 0; j < w; ++j) add += wsum[j];
    if (i < NB_SCAN) bsum[i] = x - v + add;
}

__global__ void scan3_kernel(int* __restrict__ rp, const int* __restrict__ bsum,
                             int* __restrict__ cursor) {
    int i = blockIdx.x * 256 + threadIdx.x;
    if (i < N_NODES) {
        int v = rp[i] + bsum[blockIdx.x];
        rp[i] = v;
        cursor[i] = v;
    }
    if (i == 0) rp[N_NODES] = N_EDGES;
}

__global__ void bin_kernel(const int* __restrict__ src, const int* __restrict__ dst,
                           const float* __restrict__ dinv, int* __restrict__ cursor,
                           int2* __restrict__ meta) {
    int e = blockIdx.x * blockDim.x + threadIdx.x;
    if (e >= N_EDGES) return;
    int s = src[e], d = dst[e];
    int pos = atomicAdd(&cursor[d], 1);
    meta[pos] = make_int2(s, __float_as_int(dinv[s] * dinv[d]));
}

// ---------------- GEMM: h = x @ W   (x: [N,K], W: [K,64]) ----------------
template <int K>
__global__ void gemm_kernel(const float* __restrict__ x, const float* __restrict__ W,
                            float* __restrict__ h) {
    __shared__ float Wl[K * 64];
    for (int i = threadIdx.x; i < K * 64; i += 256) Wl[i] = W[i];
    __syncthreads();
    int node = blockIdx.x * 4 + (threadIdx.x >> 6);
    int col  = threadIdx.x & 63;
    float xr[K / 64];
#pragma unroll
    for (int j = 0; j < K / 64; ++j) xr[j] = x[node * K + j * 64 + col];
    float acc = 0.0f;
#pragma unroll
    for (int j = 0; j < K / 64; ++j) {
#pragma unroll 8
        for (int k = 0; k < 64; ++k) {
            float xv = __shfl(xr[j], k, 64);
            acc += xv * Wl[(j * 64 + k) * 64 + col];
        }
    }
    h[node * F + col] = acc;
}

// ---------------- fused: selfloop+bias + CSR-gather + ReLU + pool ----------------
// one wave per destination node; register accumulation, single write, no edge atomics
__global__ void aggregate_kernel(const float* __restrict__ h, const int2* __restrict__ meta,
                                 const int* __restrict__ rp, const float* __restrict__ dinv,
                                 const float* __restrict__ b, const int* __restrict__ batch,
                                 float* __restrict__ xout, float* __restrict__ sums) {
    int node = blockIdx.x * 4 + (threadIdx.x >> 6);
    int f = threadIdx.x & 63;
    float di = dinv[node];
    float acc = b[f] + di * di * h[node * F + f];
    int e = rp[node], end = rp[node + 1];
    for (; e + 4 <= end; e += 4) {
        int2 m0 = meta[e], m1 = meta[e + 1], m2 = meta[e + 2], m3 = meta[e + 3];
        float v0 = h[m0.x * F + f];
        float v1 = h[m1.x * F + f];
        float v2 = h[m2.x * F + f];
        float v3 = h[m3.x * F + f];
        acc += __int_as_float(m0.y) * v0 + __int_as_float(m1.y) * v1 +
               __int_as_float(m2.y) * v2 + __int_as_float(m3.y) * v3;
    }
    for (; e < end; ++e) {
        int2 m = meta[e];
        acc += __int_as_float(m.y) * h[m.x * F + f];
    }
    float v = fmaxf(acc, 0.0f);
    xout[node * F + f] = v;
    atomicAdd(&sums[batch[node] * F + f], v);
}

// ---------------- head + final ----------------
__global__ void head_kernel(const float* __restrict__ sums, const float* __restrict__ cnt,
                            const float* __restrict__ Wl1, const float* __restrict__ bl1,
                            const float* __restrict__ Wl2, const float* __restrict__ bl2,
                            const float* __restrict__ Wl3, const float* __restrict__ bl3,
                            float* __restrict__ gcat) {
    int g = blockIdx.x;
    int t = threadIdx.x;
    if (t >= 30) return;
    int l = t / 10, c = t % 10;
    const float* Wl = (l == 0) ? Wl1 : (l == 1) ? Wl2 : Wl3;
    const float* bl = (l == 0) ? bl1 : (l == 1) ? bl2 : bl3;
    float invc = 1.0f / fmaxf(cnt[g], 1.0f);
    const float* srow = sums + (long long)l * NG * F + (long long)g * F;
    float acc = bl[c];
    for (int k = 0; k < F; ++k) acc += srow[k] * invc * Wl[k * ODIM + c];
    gcat[g * 30 + t] = acc;
}

__global__ void final_kernel(const float* __restrict__ gcat, const float* __restrict__ Wf,
                             const float* __restrict__ bf, float* __restrict__ out) {
    int g = blockIdx.x * blockDim.x + threadIdx.x;
    if (g >= NG) return;
    float z[ODIM];
    float m = -1e30f;
    for (int c = 0; c < ODIM; ++c) {
        float acc = bf[c];
        for (int k = 0; k < 30; ++k) acc += gcat[g * 30 + k] * Wf[k * ODIM + c];
        z[c] = acc;
        m = fmaxf(m, acc);
    }
    float s = 0.0f;
    for (int c = 0; c < ODIM; ++c) { z[c] = expf(z[c] - m); s += z[c]; }
    float inv = 1.0f / s;
    for (int c = 0; c < ODIM; ++c) out[g * ODIM + c] = z[c] * inv;
}

extern "C" void kernel_launch(void* const* d_in, const int* in_sizes, int n_in,
                              void* d_out, int out_size, void* d_ws, size_t ws_size,
                              hipStream_t stream) {
    const float* features = (const float*)d_in[0];
    const int*   edge     = (const int*)d_in[1];
    const int*   batch    = (const int*)d_in[2];
    const float* W1 = (const float*)d_in[3];
    const float* b1 = (const float*)d_in[4];
    const float* W2 = (const float*)d_in[5];
    const float* b2 = (const float*)d_in[6];
    const float* W3 = (const float*)d_in[7];
    const float* b3 = (const float*)d_in[8];
    const float* Wl1 = (const float*)d_in[9];
    const float* bl1 = (const float*)d_in[10];
    const float* Wl2 = (const float*)d_in[11];
    const float* bl2 = (const float*)d_in[12];
    const float* Wl3 = (const float*)d_in[13];
    const float* bl3 = (const float*)d_in[14];
    const float* Wf = (const float*)d_in[15];
    const float* bf = (const float*)d_in[16];

    const int* src = edge;
    const int* dst = edge + N_EDGES;

    // workspace (4B units). zero region first: [deg | sums | cnt]
    char* wsb = (char*)d_ws;
    int*   deg    = (int*)wsb;                          // N
    float* sums   = (float*)(deg + N_NODES);            // 3*NG*F
    float* cnt    = sums + 3 * NG * F;                  // NG
    float* dinv   = cnt + NG;                           // N
    int*   rp     = (int*)(dinv + N_NODES);             // N+1
    int*   pad    = rp + N_NODES + 1;                   // +1 keeps evenness
    int*   cursor = pad + 1;                            // N
    int*   bsum   = cursor + N_NODES;                   // 512
    float* gcat   = (float*)(bsum + 512);               // NG*30
    float* X      = gcat + NG * 30;                     // N*F
    float* H      = X + (long long)N_NODES * F;         // N*F
    int2*  meta   = (int2*)(H + (long long)N_NODES * F);// E int2 (8B aligned: even offset)

    const int zeroN = N_NODES + 3 * NG * F + NG;
    hipLaunchKernelGGL(zero_kernel, dim3((zeroN + 255) / 256), dim3(256), 0, stream, (float*)deg, zeroN);
    hipLaunchKernelGGL(deg_kernel, dim3((N_EDGES + 255) / 256), dim3(256), 0, stream, dst, deg);
    hipLaunchKernelGGL(dinv_kernel, dim3((N_NODES + 255) / 256), dim3(256), 0, stream, deg, dinv);
    hipLaunchKernelGGL(cnt_kernel, dim3((N_NODES + 255) / 256), dim3(256), 0, stream, batch, cnt);
    hipLaunchKernelGGL(scan1_kernel, dim3(NB_SCAN), dim3(256), 0, stream, deg, rp, bsum);
    hipLaunchKernelGGL(scan2_kernel, dim3(1), dim3(512), 0, stream, bsum);
    hipLaunchKernelGGL(scan3_kernel, dim3(NB_SCAN), dim3(256), 0, stream, rp, bsum, cursor);
    hipLaunchKernelGGL(bin_kernel, dim3((N_EDGES + 255) / 256), dim3(256), 0, stream, src, dst, dinv, cursor, meta);

    const int nodeBlocks = N_NODES / 4;  // 25000

    // ---- layer 1 ----
    hipLaunchKernelGGL((gemm_kernel<INDIM>), dim3(nodeBlocks), dim3(256), 0, stream, features, W1, H);
    hipLaunchKernelGGL(aggregate_kernel, dim3(nodeBlocks), dim3(256), 0, stream, H, meta, rp, dinv, b1, batch, X, sums + 0 * NG * F);
    // ---- layer 2 ----
    hipLaunchKernelGGL((gemm_kernel<F>), dim3(nodeBlocks), dim3(256), 0, stream, X, W2, H);
    hipLaunchKernelGGL(aggregate_kernel, dim3(nodeBlocks), dim3(256), 0, stream, H, meta, rp, dinv, b2, batch, X, sums + 1 * NG * F);
    // ---- layer 3 ----
    hipLaunchKernelGGL((gemm_kernel<F>), dim3(nodeBlocks), dim3(256), 0, stream, X, W3, H);
    hipLaunchKernelGGL(aggregate_kernel, dim3(nodeBlocks), dim3(256), 0, stream, H, meta, rp, dinv, b3, batch, X, sums + 2 * NG * F);

    // ---- heads + final ----
    hipLaunchKernelGGL(head_kernel, dim3(NG), dim3(32), 0, stream, sums, cnt,
                       Wl1, bl1, Wl2, bl2, Wl3, bl3, gcat);
    hipLaunchKernelGGL(final_kernel, dim3((NG + 255) / 256), dim3(256), 0, stream, gcat, Wf, bf, (float*)d_out);
}

// Round 3
// 803.218 us; speedup vs baseline: 2.1327x; 1.1894x over previous
//
#include <hip/hip_runtime.h>
#include <math.h>

#define N_NODES 100000
#define N_EDGES 1600000
#define INDIM 128
#define F 64
#define ODIM 10
#define NG 512
#define NB_SCAN ((N_NODES + 255) / 256)  // 391

// ---------------- utility ----------------
__global__ void zero_kernel(float* p, int n) {
    int i = blockIdx.x * blockDim.x + threadIdx.x;
    if (i < n) p[i] = 0.0f;
}

__global__ void deg_kernel(const int* __restrict__ dst, int* __restrict__ deg) {
    int e = blockIdx.x * blockDim.x + threadIdx.x;
    if (e < N_EDGES) atomicAdd(&deg[dst[e]], 1);
}

__global__ void dinv_kernel(const int* __restrict__ deg, float* __restrict__ dinv) {
    int i = blockIdx.x * blockDim.x + threadIdx.x;
    if (i < N_NODES) dinv[i] = rsqrtf((float)deg[i] + 1.0f);  // +1 self-loop
}

__global__ void cnt_kernel(const int* __restrict__ batch, float* __restrict__ cnt) {
    int i = blockIdx.x * blockDim.x + threadIdx.x;
    if (i < N_NODES) atomicAdd(&cnt[batch[i]], 1.0f);
}

// ---------------- CSR build: scan of degrees, then bin edges ----------------
__global__ void scan1_kernel(const int* __restrict__ deg, int* __restrict__ rp,
                             int* __restrict__ bsum) {
    int i = blockIdx.x * 256 + threadIdx.x;
    int v = (i < N_NODES) ? deg[i] : 0;
    int lane = threadIdx.x & 63, w = threadIdx.x >> 6;
    int x = v;
#pragma unroll
    for (int off = 1; off < 64; off <<= 1) {
        int y = __shfl_up(x, off, 64);
        if (lane >= off) x += y;
    }
    __shared__ int wsum[4];
    if (lane == 63) wsum[w] = x;
    __syncthreads();
    int add = 0;
    for (int j = 0; j < w; ++j) add += wsum[j];
    if (i < N_NODES) rp[i] = x - v + add;          // block-local exclusive
    if (threadIdx.x == 255) bsum[blockIdx.x] = x + add;  // block total
}

__global__ void scan2_kernel(int* __restrict__ bsum) {  // 1 block, 512 thr, in-place exclusive
    int i = threadIdx.x;
    int v = (i < NB_SCAN) ? bsum[i] : 0;
    int lane = i & 63, w = i >> 6;
    int x = v;
#pragma unroll
    for (int off = 1; off < 64; off <<= 1) {
        int y = __shfl_up(x, off, 64);
        if (lane >= off) x += y;
    }
    __shared__ int wsum[8];
    if (lane == 63) wsum[w] = x;
    __syncthreads();
    int add = 0;
    for (int j = 0; j < w; ++j) add += wsum[j];
    if (i < NB_SCAN) bsum[i] = x - v + add;
}

__global__ void scan3_kernel(int* __restrict__ rp, const int* __restrict__ bsum,
                             int* __restrict__ cursor) {
    int i = blockIdx.x * 256 + threadIdx.x;
    if (i < N_NODES) {
        int v = rp[i] + bsum[blockIdx.x];
        rp[i] = v;
        cursor[i] = v;
    }
    if (i == 0) rp[N_NODES] = N_EDGES;
}

__global__ void bin_kernel(const int* __restrict__ src, const int* __restrict__ dst,
                           const float* __restrict__ dinv, int* __restrict__ cursor,
                           int2* __restrict__ meta) {
    int e = blockIdx.x * blockDim.x + threadIdx.x;
    if (e >= N_EDGES) return;
    int s = src[e], d = dst[e];
    int pos = atomicAdd(&cursor[d], 1);
    meta[pos] = make_int2(s, __float_as_int(dinv[s] * dinv[d]));
}

// ---------------- GEMM: h = x @ W   (x: [N,K], W: [K,64]) ----------------
// block = 256 thr = 4 waves; block owns 64 nodes. lane = node, wave = 16-col group.
// x tile staged in LDS (pad K+1 -> conflict-free b32 reads); W rows via wave-uniform
// scalar loads (s_load_dwordx16); 16 accumulators per thread -> VALU-bound.
template <int K>
__global__ void __launch_bounds__(256) gemm_kernel(const float* __restrict__ x,
                                                   const float* __restrict__ W,
                                                   float* __restrict__ h) {
    __shared__ float xs[64][K + 1];
    int node0 = blockIdx.x * 64;
    for (int idx = threadIdx.x; idx < 64 * K; idx += 256) {
        int n = idx / K, k = idx % K;
        int gn = node0 + n;
        if (gn >= N_NODES) gn = N_NODES - 1;
        xs[n][k] = x[(long long)gn * K + k];
    }
    __syncthreads();
    int lane = threadIdx.x & 63;
    int cg = (threadIdx.x >> 6) * 16;
    int node = node0 + lane;
    float acc[16];
#pragma unroll
    for (int c = 0; c < 16; ++c) acc[c] = 0.0f;
#pragma unroll 4
    for (int k = 0; k < K; ++k) {
        float xv = xs[lane][k];
        const float* wr = &W[k * 64 + cg];
#pragma unroll
        for (int c = 0; c < 16; ++c) acc[c] = fmaf(wr[c], xv, acc[c]);
    }
    if (node < N_NODES) {
        float4* hp = (float4*)&h[(long long)node * 64 + cg];
#pragma unroll
        for (int c = 0; c < 4; ++c)
            hp[c] = make_float4(acc[4 * c], acc[4 * c + 1], acc[4 * c + 2], acc[4 * c + 3]);
    }
}

// ---------------- fused: selfloop+bias + CSR-gather + ReLU + pool ----------------
__global__ void aggregate_kernel(const float* __restrict__ h, const int2* __restrict__ meta,
                                 const int* __restrict__ rp, const float* __restrict__ dinv,
                                 const float* __restrict__ b, const int* __restrict__ batch,
                                 float* __restrict__ xout, float* __restrict__ sums) {
    int node = blockIdx.x * 4 + (threadIdx.x >> 6);
    int f = threadIdx.x & 63;
    float di = dinv[node];
    float acc = b[f] + di * di * h[node * F + f];
    int e = rp[node], end = rp[node + 1];
    for (; e + 4 <= end; e += 4) {
        int2 m0 = meta[e], m1 = meta[e + 1], m2 = meta[e + 2], m3 = meta[e + 3];
        float v0 = h[m0.x * F + f];
        float v1 = h[m1.x * F + f];
        float v2 = h[m2.x * F + f];
        float v3 = h[m3.x * F + f];
        acc += __int_as_float(m0.y) * v0 + __int_as_float(m1.y) * v1 +
               __int_as_float(m2.y) * v2 + __int_as_float(m3.y) * v3;
    }
    for (; e < end; ++e) {
        int2 m = meta[e];
        acc += __int_as_float(m.y) * h[m.x * F + f];
    }
    float v = fmaxf(acc, 0.0f);
    xout[node * F + f] = v;
    atomicAdd(&sums[batch[node] * F + f], v);
}

// ---------------- head + final ----------------
__global__ void head_kernel(const float* __restrict__ sums, const float* __restrict__ cnt,
                            const float* __restrict__ Wl1, const float* __restrict__ bl1,
                            const float* __restrict__ Wl2, const float* __restrict__ bl2,
                            const float* __restrict__ Wl3, const float* __restrict__ bl3,
                            float* __restrict__ gcat) {
    int g = blockIdx.x;
    int t = threadIdx.x;
    if (t >= 30) return;
    int l = t / 10, c = t % 10;
    const float* Wl = (l == 0) ? Wl1 : (l == 1) ? Wl2 : Wl3;
    const float* bl = (l == 0) ? bl1 : (l == 1) ? bl2 : bl3;
    float invc = 1.0f / fmaxf(cnt[g], 1.0f);
    const float* srow = sums + (long long)l * NG * F + (long long)g * F;
    float acc = bl[c];
    for (int k = 0; k < F; ++k) acc += srow[k] * invc * Wl[k * ODIM + c];
    gcat[g * 30 + t] = acc;
}

__global__ void final_kernel(const float* __restrict__ gcat, const float* __restrict__ Wf,
                             const float* __restrict__ bf, float* __restrict__ out) {
    int g = blockIdx.x * blockDim.x + threadIdx.x;
    if (g >= NG) return;
    float z[ODIM];
    float m = -1e30f;
    for (int c = 0; c < ODIM; ++c) {
        float acc = bf[c];
        for (int k = 0; k < 30; ++k) acc += gcat[g * 30 + k] * Wf[k * ODIM + c];
        z[c] = acc;
        m = fmaxf(m, acc);
    }
    float s = 0.0f;
    for (int c = 0; c < ODIM; ++c) { z[c] = expf(z[c] - m); s += z[c]; }
    float inv = 1.0f / s;
    for (int c = 0; c < ODIM; ++c) out[g * ODIM + c] = z[c] * inv;
}

extern "C" void kernel_launch(void* const* d_in, const int* in_sizes, int n_in,
                              void* d_out, int out_size, void* d_ws, size_t ws_size,
                              hipStream_t stream) {
    const float* features = (const float*)d_in[0];
    const int*   edge     = (const int*)d_in[1];
    const int*   batch    = (const int*)d_in[2];
    const float* W1 = (const float*)d_in[3];
    const float* b1 = (const float*)d_in[4];
    const float* W2 = (const float*)d_in[5];
    const float* b2 = (const float*)d_in[6];
    const float* W3 = (const float*)d_in[7];
    const float* b3 = (const float*)d_in[8];
    const float* Wl1 = (const float*)d_in[9];
    const float* bl1 = (const float*)d_in[10];
    const float* Wl2 = (const float*)d_in[11];
    const float* bl2 = (const float*)d_in[12];
    const float* Wl3 = (const float*)d_in[13];
    const float* bl3 = (const float*)d_in[14];
    const float* Wf = (const float*)d_in[15];
    const float* bf = (const float*)d_in[16];

    const int* src = edge;
    const int* dst = edge + N_EDGES;

    // workspace (4B units). zero region first: [deg | sums | cnt]
    char* wsb = (char*)d_ws;
    int*   deg    = (int*)wsb;                          // N
    float* sums   = (float*)(deg + N_NODES);            // 3*NG*F
    float* cnt    = sums + 3 * NG * F;                  // NG
    float* dinv   = cnt + NG;                           // N
    int*   rp     = (int*)(dinv + N_NODES);             // N+1
    int*   pad    = rp + N_NODES + 1;                   // +1 keeps evenness
    int*   cursor = pad + 1;                            // N
    int*   bsum   = cursor + N_NODES;                   // 512
    float* gcat   = (float*)(bsum + 512);               // NG*30
    float* X      = gcat + NG * 30;                     // N*F
    float* H      = X + (long long)N_NODES * F;         // N*F
    int2*  meta   = (int2*)(H + (long long)N_NODES * F);// E int2 (8B aligned: even offset)

    const int zeroN = N_NODES + 3 * NG * F + NG;
    hipLaunchKernelGGL(zero_kernel, dim3((zeroN + 255) / 256), dim3(256), 0, stream, (float*)deg, zeroN);
    hipLaunchKernelGGL(deg_kernel, dim3((N_EDGES + 255) / 256), dim3(256), 0, stream, dst, deg);
    hipLaunchKernelGGL(dinv_kernel, dim3((N_NODES + 255) / 256), dim3(256), 0, stream, deg, dinv);
    hipLaunchKernelGGL(cnt_kernel, dim3((N_NODES + 255) / 256), dim3(256), 0, stream, batch, cnt);
    hipLaunchKernelGGL(scan1_kernel, dim3(NB_SCAN), dim3(256), 0, stream, deg, rp, bsum);
    hipLaunchKernelGGL(scan2_kernel, dim3(1), dim3(512), 0, stream, bsum);
    hipLaunchKernelGGL(scan3_kernel, dim3(NB_SCAN), dim3(256), 0, stream, rp, bsum, cursor);
    hipLaunchKernelGGL(bin_kernel, dim3((N_EDGES + 255) / 256), dim3(256), 0, stream, src, dst, dinv, cursor, meta);

    const int nodeBlocks  = N_NODES / 4;                 // 25000 (aggregate)
    const int gemmBlocks  = (N_NODES + 63) / 64;         // 1563

    // ---- layer 1 ----
    hipLaunchKernelGGL((gemm_kernel<INDIM>), dim3(gemmBlocks), dim3(256), 0, stream, features, W1, H);
    hipLaunchKernelGGL(aggregate_kernel, dim3(nodeBlocks), dim3(256), 0, stream, H, meta, rp, dinv, b1, batch, X, sums + 0 * NG * F);
    // ---- layer 2 ----
    hipLaunchKernelGGL((gemm_kernel<F>), dim3(gemmBlocks), dim3(256), 0, stream, X, W2, H);
    hipLaunchKernelGGL(aggregate_kernel, dim3(nodeBlocks), dim3(256), 0, stream, H, meta, rp, dinv, b2, batch, X, sums + 1 * NG * F);
    // ---- layer 3 ----
    hipLaunchKernelGGL((gemm_kernel<F>), dim3(gemmBlocks), dim3(256), 0, stream, X, W3, H);
    hipLaunchKernelGGL(aggregate_kernel, dim3(nodeBlocks), dim3(256), 0, stream, H, meta, rp, dinv, b3, batch, X, sums + 2 * NG * F);

    // ---- heads + final ----
    hipLaunchKernelGGL(head_kernel, dim3(NG), dim3(32), 0, stream, sums, cnt,
                       Wl1, bl1, Wl2, bl2, Wl3, bl3, gcat);
    hipLaunchKernelGGL(final_kernel, dim3((NG + 255) / 256), dim3(256), 0, stream, gcat, Wf, bf, (float*)d_out);
}

// Round 4
// 687.367 us; speedup vs baseline: 2.4921x; 1.1685x over previous
//
#include <hip/hip_runtime.h>
#include <math.h>

#define N_NODES 100000
#define N_EDGES 1600000
#define INDIM 128
#define F 64
#define ODIM 10
#define NG 512
#define NB_SCAN ((N_NODES + 255) / 256)  // 391

// ---------------- utility ----------------
__global__ void zero_kernel(float* p, int n) {
    int i = blockIdx.x * blockDim.x + threadIdx.x;
    if (i < n) p[i] = 0.0f;
}

__global__ void deg_kernel(const int* __restrict__ dst, int* __restrict__ deg) {
    int e = blockIdx.x * blockDim.x + threadIdx.x;
    if (e < N_EDGES) atomicAdd(&deg[dst[e]], 1);
}

__global__ void dinv_kernel(const int* __restrict__ deg, float* __restrict__ dinv) {
    int i = blockIdx.x * blockDim.x + threadIdx.x;
    if (i < N_NODES) dinv[i] = rsqrtf((float)deg[i] + 1.0f);  // +1 self-loop
}

__global__ void cnt_kernel(const int* __restrict__ batch, float* __restrict__ cnt) {
    int i = blockIdx.x * blockDim.x + threadIdx.x;
    if (i < N_NODES) atomicAdd(&cnt[batch[i]], 1.0f);
}

// ---------------- CSR build: scan of degrees, then bin edges ----------------
__global__ void scan1_kernel(const int* __restrict__ deg, int* __restrict__ rp,
                             int* __restrict__ bsum) {
    int i = blockIdx.x * 256 + threadIdx.x;
    int v = (i < N_NODES) ? deg[i] : 0;
    int lane = threadIdx.x & 63, w = threadIdx.x >> 6;
    int x = v;
#pragma unroll
    for (int off = 1; off < 64; off <<= 1) {
        int y = __shfl_up(x, off, 64);
        if (lane >= off) x += y;
    }
    __shared__ int wsum[4];
    if (lane == 63) wsum[w] = x;
    __syncthreads();
    int add = 0;
    for (int j = 0; j < w; ++j) add += wsum[j];
    if (i < N_NODES) rp[i] = x - v + add;          // block-local exclusive
    if (threadIdx.x == 255) bsum[blockIdx.x] = x + add;  // block total
}

__global__ void scan2_kernel(int* __restrict__ bsum) {  // 1 block, 512 thr, in-place exclusive
    int i = threadIdx.x;
    int v = (i < NB_SCAN) ? bsum[i] : 0;
    int lane = i & 63, w = i >> 6;
    int x = v;
#pragma unroll
    for (int off = 1; off < 64; off <<= 1) {
        int y = __shfl_up(x, off, 64);
        if (lane >= off) x += y;
    }
    __shared__ int wsum[8];
    if (lane == 63) wsum[w] = x;
    __syncthreads();
    int add = 0;
    for (int j = 0; j < w; ++j) add += wsum[j];
    if (i < NB_SCAN) bsum[i] = x - v + add;
}

__global__ void scan3_kernel(int* __restrict__ rp, const int* __restrict__ bsum,
                             int* __restrict__ cursor) {
    int i = blockIdx.x * 256 + threadIdx.x;
    if (i < N_NODES) {
        int v = rp[i] + bsum[blockIdx.x];
        rp[i] = v;
        cursor[i] = v;
    }
    if (i == 0) rp[N_NODES] = N_EDGES;
}

__global__ void bin_kernel(const int* __restrict__ src, const int* __restrict__ dst,
                           const float* __restrict__ dinv, int* __restrict__ cursor,
                           int2* __restrict__ meta) {
    int e = blockIdx.x * blockDim.x + threadIdx.x;
    if (e >= N_EDGES) return;
    int s = src[e], d = dst[e];
    int pos = atomicAdd(&cursor[d], 1);
    meta[pos] = make_int2(s, __float_as_int(dinv[s] * dinv[d]));
}

// ---------------- GEMM: h = x @ W   (x: [N,K], W: [K,64]) ----------------
// Register outer-product, no LDS, no scalar loads on the critical path.
// Block = 256 thr; tile = 64 nodes x 64 cols; thread = 4 nodes x 4 cols (16 acc).
// Per 4-k chunk: 4 float4 x-loads (node rows, 16B aligned) + 4 float4 W-loads
// -> 64 FMA per 8 VMEM; W is L1-hot, x broadcast 16-way within the wave.
template <int K>
__global__ void __launch_bounds__(256) gemm_kernel(const float* __restrict__ x,
                                                   const float* __restrict__ W,
                                                   float* __restrict__ h) {
    int tid = threadIdx.x;
    int tn = tid >> 4;          // 0..15 -> node group
    int tc = tid & 15;          // 0..15 -> col group
    int n0 = blockIdx.x * 64 + tn * 4;
    float acc[4][4];
#pragma unroll
    for (int i = 0; i < 4; ++i)
#pragma unroll
        for (int j = 0; j < 4; ++j) acc[i][j] = 0.0f;

    int gn[4];
#pragma unroll
    for (int i = 0; i < 4; ++i) {
        int n = n0 + i;
        gn[i] = (n < N_NODES) ? n : (N_NODES - 1);  // clamp; garbage discarded at store
    }

#pragma unroll 2
    for (int k = 0; k < K; k += 4) {
        float4 xv[4], wv[4];
#pragma unroll
        for (int i = 0; i < 4; ++i)
            xv[i] = *(const float4*)&x[gn[i] * K + k];
#pragma unroll
        for (int j = 0; j < 4; ++j)
            wv[j] = *(const float4*)&W[(k + j) * 64 + tc * 4];
#pragma unroll
        for (int i = 0; i < 4; ++i) {
            acc[i][0] = fmaf(xv[i].x, wv[0].x, acc[i][0]);
            acc[i][1] = fmaf(xv[i].x, wv[0].y, acc[i][1]);
            acc[i][2] = fmaf(xv[i].x, wv[0].z, acc[i][2]);
            acc[i][3] = fmaf(xv[i].x, wv[0].w, acc[i][3]);
            acc[i][0] = fmaf(xv[i].y, wv[1].x, acc[i][0]);
            acc[i][1] = fmaf(xv[i].y, wv[1].y, acc[i][1]);
            acc[i][2] = fmaf(xv[i].y, wv[1].z, acc[i][2]);
            acc[i][3] = fmaf(xv[i].y, wv[1].w, acc[i][3]);
            acc[i][0] = fmaf(xv[i].z, wv[2].x, acc[i][0]);
            acc[i][1] = fmaf(xv[i].z, wv[2].y, acc[i][1]);
            acc[i][2] = fmaf(xv[i].z, wv[2].z, acc[i][2]);
            acc[i][3] = fmaf(xv[i].z, wv[2].w, acc[i][3]);
            acc[i][0] = fmaf(xv[i].w, wv[3].x, acc[i][0]);
            acc[i][1] = fmaf(xv[i].w, wv[3].y, acc[i][1]);
            acc[i][2] = fmaf(xv[i].w, wv[3].z, acc[i][2]);
            acc[i][3] = fmaf(xv[i].w, wv[3].w, acc[i][3]);
        }
    }
#pragma unroll
    for (int i = 0; i < 4; ++i) {
        int n = n0 + i;
        if (n < N_NODES)
            *(float4*)&h[n * 64 + tc * 4] =
                make_float4(acc[i][0], acc[i][1], acc[i][2], acc[i][3]);
    }
}

// ---------------- fused: selfloop+bias + CSR-gather + ReLU + pool ----------------
__global__ void aggregate_kernel(const float* __restrict__ h, const int2* __restrict__ meta,
                                 const int* __restrict__ rp, const float* __restrict__ dinv,
                                 const float* __restrict__ b, const int* __restrict__ batch,
                                 float* __restrict__ xout, float* __restrict__ sums) {
    int node = blockIdx.x * 4 + (threadIdx.x >> 6);
    int f = threadIdx.x & 63;
    float di = dinv[node];
    float acc = b[f] + di * di * h[node * F + f];
    int e = rp[node], end = rp[node + 1];
    for (; e + 4 <= end; e += 4) {
        int2 m0 = meta[e], m1 = meta[e + 1], m2 = meta[e + 2], m3 = meta[e + 3];
        float v0 = h[m0.x * F + f];
        float v1 = h[m1.x * F + f];
        float v2 = h[m2.x * F + f];
        float v3 = h[m3.x * F + f];
        acc += __int_as_float(m0.y) * v0 + __int_as_float(m1.y) * v1 +
               __int_as_float(m2.y) * v2 + __int_as_float(m3.y) * v3;
    }
    for (; e < end; ++e) {
        int2 m = meta[e];
        acc += __int_as_float(m.y) * h[m.x * F + f];
    }
    float v = fmaxf(acc, 0.0f);
    xout[node * F + f] = v;
    atomicAdd(&sums[batch[node] * F + f], v);
}

// ---------------- head + final ----------------
__global__ void head_kernel(const float* __restrict__ sums, const float* __restrict__ cnt,
                            const float* __restrict__ Wl1, const float* __restrict__ bl1,
                            const float* __restrict__ Wl2, const float* __restrict__ bl2,
                            const float* __restrict__ Wl3, const float* __restrict__ bl3,
                            float* __restrict__ gcat) {
    int g = blockIdx.x;
    int t = threadIdx.x;
    if (t >= 30) return;
    int l = t / 10, c = t % 10;
    const float* Wl = (l == 0) ? Wl1 : (l == 1) ? Wl2 : Wl3;
    const float* bl = (l == 0) ? bl1 : (l == 1) ? bl2 : bl3;
    float invc = 1.0f / fmaxf(cnt[g], 1.0f);
    const float* srow = sums + (long long)l * NG * F + (long long)g * F;
    float acc = bl[c];
    for (int k = 0; k < F; ++k) acc += srow[k] * invc * Wl[k * ODIM + c];
    gcat[g * 30 + t] = acc;
}

__global__ void final_kernel(const float* __restrict__ gcat, const float* __restrict__ Wf,
                             const float* __restrict__ bf, float* __restrict__ out) {
    int g = blockIdx.x * blockDim.x + threadIdx.x;
    if (g >= NG) return;
    float z[ODIM];
    float m = -1e30f;
    for (int c = 0; c < ODIM; ++c) {
        float acc = bf[c];
        for (int k = 0; k < 30; ++k) acc += gcat[g * 30 + k] * Wf[k * ODIM + c];
        z[c] = acc;
        m = fmaxf(m, acc);
    }
    float s = 0.0f;
    for (int c = 0; c < ODIM; ++c) { z[c] = expf(z[c] - m); s += z[c]; }
    float inv = 1.0f / s;
    for (int c = 0; c < ODIM; ++c) out[g * ODIM + c] = z[c] * inv;
}

extern "C" void kernel_launch(void* const* d_in, const int* in_sizes, int n_in,
                              void* d_out, int out_size, void* d_ws, size_t ws_size,
                              hipStream_t stream) {
    const float* features = (const float*)d_in[0];
    const int*   edge     = (const int*)d_in[1];
    const int*   batch    = (const int*)d_in[2];
    const float* W1 = (const float*)d_in[3];
    const float* b1 = (const float*)d_in[4];
    const float* W2 = (const float*)d_in[5];
    const float* b2 = (const float*)d_in[6];
    const float* W3 = (const float*)d_in[7];
    const float* b3 = (const float*)d_in[8];
    const float* Wl1 = (const float*)d_in[9];
    const float* bl1 = (const float*)d_in[10];
    const float* Wl2 = (const float*)d_in[11];
    const float* bl2 = (const float*)d_in[12];
    const float* Wl3 = (const float*)d_in[13];
    const float* bl3 = (const float*)d_in[14];
    const float* Wf = (const float*)d_in[15];
    const float* bf = (const float*)d_in[16];

    const int* src = edge;
    const int* dst = edge + N_EDGES;

    // workspace (4B units). zero region first: [deg | sums | cnt]
    char* wsb = (char*)d_ws;
    int*   deg    = (int*)wsb;                          // N
    float* sums   = (float*)(deg + N_NODES);            // 3*NG*F
    float* cnt    = sums + 3 * NG * F;                  // NG
    float* dinv   = cnt + NG;                           // N
    int*   rp     = (int*)(dinv + N_NODES);             // N+1
    int*   pad    = rp + N_NODES + 1;                   // +1 keeps evenness
    int*   cursor = pad + 1;                            // N
    int*   bsum   = cursor + N_NODES;                   // 512
    float* gcat   = (float*)(bsum + 512);               // NG*30
    float* X      = gcat + NG * 30;                     // N*F
    float* H      = X + (long long)N_NODES * F;         // N*F
    int2*  meta   = (int2*)(H + (long long)N_NODES * F);// E int2 (8B aligned: even offset)

    const int zeroN = N_NODES + 3 * NG * F + NG;
    hipLaunchKernelGGL(zero_kernel, dim3((zeroN + 255) / 256), dim3(256), 0, stream, (float*)deg, zeroN);
    hipLaunchKernelGGL(deg_kernel, dim3((N_EDGES + 255) / 256), dim3(256), 0, stream, dst, deg);
    hipLaunchKernelGGL(dinv_kernel, dim3((N_NODES + 255) / 256), dim3(256), 0, stream, deg, dinv);
    hipLaunchKernelGGL(cnt_kernel, dim3((N_NODES + 255) / 256), dim3(256), 0, stream, batch, cnt);
    hipLaunchKernelGGL(scan1_kernel, dim3(NB_SCAN), dim3(256), 0, stream, deg, rp, bsum);
    hipLaunchKernelGGL(scan2_kernel, dim3(1), dim3(512), 0, stream, bsum);
    hipLaunchKernelGGL(scan3_kernel, dim3(NB_SCAN), dim3(256), 0, stream, rp, bsum, cursor);
    hipLaunchKernelGGL(bin_kernel, dim3((N_EDGES + 255) / 256), dim3(256), 0, stream, src, dst, dinv, cursor, meta);

    const int nodeBlocks  = N_NODES / 4;                 // 25000 (aggregate)
    const int gemmBlocks  = (N_NODES + 63) / 64;         // 1563

    // ---- layer 1 ----
    hipLaunchKernelGGL((gemm_kernel<INDIM>), dim3(gemmBlocks), dim3(256), 0, stream, features, W1, H);
    hipLaunchKernelGGL(aggregate_kernel, dim3(nodeBlocks), dim3(256), 0, stream, H, meta, rp, dinv, b1, batch, X, sums + 0 * NG * F);
    // ---- layer 2 ----
    hipLaunchKernelGGL((gemm_kernel<F>), dim3(gemmBlocks), dim3(256), 0, stream, X, W2, H);
    hipLaunchKernelGGL(aggregate_kernel, dim3(nodeBlocks), dim3(256), 0, stream, H, meta, rp, dinv, b2, batch, X, sums + 1 * NG * F);
    // ---- layer 3 ----
    hipLaunchKernelGGL((gemm_kernel<F>), dim3(gemmBlocks), dim3(256), 0, stream, X, W3, H);
    hipLaunchKernelGGL(aggregate_kernel, dim3(nodeBlocks), dim3(256), 0, stream, H, meta, rp, dinv, b3, batch, X, sums + 2 * NG * F);

    // ---- heads + final ----
    hipLaunchKernelGGL(head_kernel, dim3(NG), dim3(32), 0, stream, sums, cnt,
                       Wl1, bl1, Wl2, bl2, Wl3, bl3, gcat);
    hipLaunchKernelGGL(final_kernel, dim3((NG + 255) / 256), dim3(256), 0, stream, gcat, Wf, bf, (float*)d_out);
}

// Round 5
// 659.503 us; speedup vs baseline: 2.5974x; 1.0422x over previous
//
#include <hip/hip_runtime.h>
#include <math.h>

#define N_NODES 100000
#define N_EDGES 1600000
#define INDIM 128
#define F 64
#define ODIM 10
#define NG 512
#define NB_SCAN ((N_NODES + 255) / 256)  // 391

// ---------------- utility ----------------
__global__ void zero_kernel(float* p, int n) {
    int i = blockIdx.x * blockDim.x + threadIdx.x;
    if (i < n) p[i] = 0.0f;
}

__global__ void deg_kernel(const int* __restrict__ dst, int* __restrict__ deg) {
    int e = blockIdx.x * blockDim.x + threadIdx.x;
    if (e < N_EDGES) atomicAdd(&deg[dst[e]], 1);
}

__global__ void dinv_kernel(const int* __restrict__ deg, float* __restrict__ dinv) {
    int i = blockIdx.x * blockDim.x + threadIdx.x;
    if (i < N_NODES) dinv[i] = rsqrtf((float)deg[i] + 1.0f);  // +1 self-loop
}

__global__ void cnt_kernel(const int* __restrict__ batch, float* __restrict__ cnt) {
    int i = blockIdx.x * blockDim.x + threadIdx.x;
    if (i < N_NODES) atomicAdd(&cnt[batch[i]], 1.0f);
}

// ---------------- CSR build: scan of degrees, then bin edges ----------------
__global__ void scan1_kernel(const int* __restrict__ deg, int* __restrict__ rp,
                             int* __restrict__ bsum) {
    int i = blockIdx.x * 256 + threadIdx.x;
    int v = (i < N_NODES) ? deg[i] : 0;
    int lane = threadIdx.x & 63, w = threadIdx.x >> 6;
    int x = v;
#pragma unroll
    for (int off = 1; off < 64; off <<= 1) {
        int y = __shfl_up(x, off, 64);
        if (lane >= off) x += y;
    }
    __shared__ int wsum[4];
    if (lane == 63) wsum[w] = x;
    __syncthreads();
    int add = 0;
    for (int j = 0; j < w; ++j) add += wsum[j];
    if (i < N_NODES) rp[i] = x - v + add;          // block-local exclusive
    if (threadIdx.x == 255) bsum[blockIdx.x] = x + add;  // block total
}

__global__ void scan2_kernel(int* __restrict__ bsum) {  // 1 block, 512 thr, in-place exclusive
    int i = threadIdx.x;
    int v = (i < NB_SCAN) ? bsum[i] : 0;
    int lane = i & 63, w = i >> 6;
    int x = v;
#pragma unroll
    for (int off = 1; off < 64; off <<= 1) {
        int y = __shfl_up(x, off, 64);
        if (lane >= off) x += y;
    }
    __shared__ int wsum[8];
    if (lane == 63) wsum[w] = x;
    __syncthreads();
    int add = 0;
    for (int j = 0; j < w; ++j) add += wsum[j];
    if (i < NB_SCAN) bsum[i] = x - v + add;
}

__global__ void scan3_kernel(int* __restrict__ rp, const int* __restrict__ bsum,
                             int* __restrict__ cursor) {
    int i = blockIdx.x * 256 + threadIdx.x;
    if (i < N_NODES) {
        int v = rp[i] + bsum[blockIdx.x];
        rp[i] = v;
        cursor[i] = v;
    }
    if (i == 0) rp[N_NODES] = N_EDGES;
}

__global__ void bin_kernel(const int* __restrict__ src, const int* __restrict__ dst,
                           const float* __restrict__ dinv, int* __restrict__ cursor,
                           int2* __restrict__ meta) {
    int e = blockIdx.x * blockDim.x + threadIdx.x;
    if (e >= N_EDGES) return;
    int s = src[e], d = dst[e];
    int pos = atomicAdd(&cursor[d], 1);
    meta[pos] = make_int2(s, __float_as_int(dinv[s] * dinv[d]));
}

// ---------------- GEMM: h = x @ W   (x: [N,K], W: [K,64]) ----------------
// Register outer-product, no LDS, no scalar loads on the critical path.
template <int K>
__global__ void __launch_bounds__(256) gemm_kernel(const float* __restrict__ x,
                                                   const float* __restrict__ W,
                                                   float* __restrict__ h) {
    int tid = threadIdx.x;
    int tn = tid >> 4;          // 0..15 -> node group
    int tc = tid & 15;          // 0..15 -> col group
    int n0 = blockIdx.x * 64 + tn * 4;
    float acc[4][4];
#pragma unroll
    for (int i = 0; i < 4; ++i)
#pragma unroll
        for (int j = 0; j < 4; ++j) acc[i][j] = 0.0f;

    int gn[4];
#pragma unroll
    for (int i = 0; i < 4; ++i) {
        int n = n0 + i;
        gn[i] = (n < N_NODES) ? n : (N_NODES - 1);  // clamp; garbage discarded at store
    }

#pragma unroll 2
    for (int k = 0; k < K; k += 4) {
        float4 xv[4], wv[4];
#pragma unroll
        for (int i = 0; i < 4; ++i)
            xv[i] = *(const float4*)&x[gn[i] * K + k];
#pragma unroll
        for (int j = 0; j < 4; ++j)
            wv[j] = *(const float4*)&W[(k + j) * 64 + tc * 4];
#pragma unroll
        for (int i = 0; i < 4; ++i) {
            acc[i][0] = fmaf(xv[i].x, wv[0].x, acc[i][0]);
            acc[i][1] = fmaf(xv[i].x, wv[0].y, acc[i][1]);
            acc[i][2] = fmaf(xv[i].x, wv[0].z, acc[i][2]);
            acc[i][3] = fmaf(xv[i].x, wv[0].w, acc[i][3]);
            acc[i][0] = fmaf(xv[i].y, wv[1].x, acc[i][0]);
            acc[i][1] = fmaf(xv[i].y, wv[1].y, acc[i][1]);
            acc[i][2] = fmaf(xv[i].y, wv[1].z, acc[i][2]);
            acc[i][3] = fmaf(xv[i].y, wv[1].w, acc[i][3]);
            acc[i][0] = fmaf(xv[i].z, wv[2].x, acc[i][0]);
            acc[i][1] = fmaf(xv[i].z, wv[2].y, acc[i][1]);
            acc[i][2] = fmaf(xv[i].z, wv[2].z, acc[i][2]);
            acc[i][3] = fmaf(xv[i].z, wv[2].w, acc[i][3]);
            acc[i][0] = fmaf(xv[i].w, wv[3].x, acc[i][0]);
            acc[i][1] = fmaf(xv[i].w, wv[3].y, acc[i][1]);
            acc[i][2] = fmaf(xv[i].w, wv[3].z, acc[i][2]);
            acc[i][3] = fmaf(xv[i].w, wv[3].w, acc[i][3]);
        }
    }
#pragma unroll
    for (int i = 0; i < 4; ++i) {
        int n = n0 + i;
        if (n < N_NODES)
            *(float4*)&h[n * 64 + tc * 4] =
                make_float4(acc[i][0], acc[i][1], acc[i][2], acc[i][3]);
    }
}

// ---------------- fused: selfloop+bias + CSR-gather + ReLU + pool ----------------
// One wave per node. Meta for up to 64 edges loaded LANE-PARALLEL (coalesced),
// distributed via __shfl (register-only), gathers issued in batches of 16
// -> 4 KB in flight per wave instead of 1 KB (latency hiding).
__global__ void aggregate_kernel(const float* __restrict__ h, const int2* __restrict__ meta,
                                 const int* __restrict__ rp, const float* __restrict__ dinv,
                                 const float* __restrict__ b, const int* __restrict__ batch,
                                 float* __restrict__ xout, float* __restrict__ sums) {
    int node = blockIdx.x * 4 + (threadIdx.x >> 6);
    int f = threadIdx.x & 63;
    int lane = f;
    float di = dinv[node];
    float acc = b[f] + di * di * h[node * F + f];
    int e = rp[node], end = rp[node + 1];
    while (e < end) {
        int cnt = end - e;
        if (cnt > 64) cnt = 64;
        int2 m = make_int2(0, 0);
        if (lane < cnt) m = meta[e + lane];
        int j = 0;
        for (; j + 16 <= cnt; j += 16) {
            float v[16];
#pragma unroll
            for (int c = 0; c < 16; ++c) {
                int s = __shfl(m.x, j + c, 64);
                v[c] = h[s * F + f];
            }
#pragma unroll
            for (int c = 0; c < 16; ++c) {
                int wi = __shfl(m.y, j + c, 64);
                acc = fmaf(__int_as_float(wi), v[c], acc);
            }
        }
        for (; j + 4 <= cnt; j += 4) {
            float v[4];
#pragma unroll
            for (int c = 0; c < 4; ++c) {
                int s = __shfl(m.x, j + c, 64);
                v[c] = h[s * F + f];
            }
#pragma unroll
            for (int c = 0; c < 4; ++c) {
                int wi = __shfl(m.y, j + c, 64);
                acc = fmaf(__int_as_float(wi), v[c], acc);
            }
        }
        for (; j < cnt; ++j) {
            int s = __shfl(m.x, j, 64);
            int wi = __shfl(m.y, j, 64);
            acc = fmaf(__int_as_float(wi), h[s * F + f], acc);
        }
        e += cnt;
    }
    float v = fmaxf(acc, 0.0f);
    xout[node * F + f] = v;
    atomicAdd(&sums[batch[node] * F + f], v);
}

// ---------------- head + final ----------------
__global__ void head_kernel(const float* __restrict__ sums, const float* __restrict__ cnt,
                            const float* __restrict__ Wl1, const float* __restrict__ bl1,
                            const float* __restrict__ Wl2, const float* __restrict__ bl2,
                            const float* __restrict__ Wl3, const float* __restrict__ bl3,
                            float* __restrict__ gcat) {
    int g = blockIdx.x;
    int t = threadIdx.x;
    if (t >= 30) return;
    int l = t / 10, c = t % 10;
    const float* Wl = (l == 0) ? Wl1 : (l == 1) ? Wl2 : Wl3;
    const float* bl = (l == 0) ? bl1 : (l == 1) ? bl2 : bl3;
    float invc = 1.0f / fmaxf(cnt[g], 1.0f);
    const float* srow = sums + (long long)l * NG * F + (long long)g * F;
    float acc = bl[c];
    for (int k = 0; k < F; ++k) acc += srow[k] * invc * Wl[k * ODIM + c];
    gcat[g * 30 + t] = acc;
}

__global__ void final_kernel(const float* __restrict__ gcat, const float* __restrict__ Wf,
                             const float* __restrict__ bf, float* __restrict__ out) {
    int g = blockIdx.x * blockDim.x + threadIdx.x;
    if (g >= NG) return;
    float z[ODIM];
    float m = -1e30f;
    for (int c = 0; c < ODIM; ++c) {
        float acc = bf[c];
        for (int k = 0; k < 30; ++k) acc += gcat[g * 30 + k] * Wf[k * ODIM + c];
        z[c] = acc;
        m = fmaxf(m, acc);
    }
    float s = 0.0f;
    for (int c = 0; c < ODIM; ++c) { z[c] = expf(z[c] - m); s += z[c]; }
    float inv = 1.0f / s;
    for (int c = 0; c < ODIM; ++c) out[g * ODIM + c] = z[c] * inv;
}

extern "C" void kernel_launch(void* const* d_in, const int* in_sizes, int n_in,
                              void* d_out, int out_size, void* d_ws, size_t ws_size,
                              hipStream_t stream) {
    const float* features = (const float*)d_in[0];
    const int*   edge     = (const int*)d_in[1];
    const int*   batch    = (const int*)d_in[2];
    const float* W1 = (const float*)d_in[3];
    const float* b1 = (const float*)d_in[4];
    const float* W2 = (const float*)d_in[5];
    const float* b2 = (const float*)d_in[6];
    const float* W3 = (const float*)d_in[7];
    const float* b3 = (const float*)d_in[8];
    const float* Wl1 = (const float*)d_in[9];
    const float* bl1 = (const float*)d_in[10];
    const float* Wl2 = (const float*)d_in[11];
    const float* bl2 = (const float*)d_in[12];
    const float* Wl3 = (const float*)d_in[13];
    const float* bl3 = (const float*)d_in[14];
    const float* Wf = (const float*)d_in[15];
    const float* bf = (const float*)d_in[16];

    const int* src = edge;
    const int* dst = edge + N_EDGES;

    // workspace (4B units). zero region first: [deg | sums | cnt]
    char* wsb = (char*)d_ws;
    int*   deg    = (int*)wsb;                          // N
    float* sums   = (float*)(deg + N_NODES);            // 3*NG*F
    float* cnt    = sums + 3 * NG * F;                  // NG
    float* dinv   = cnt + NG;                           // N
    int*   rp     = (int*)(dinv + N_NODES);             // N+1
    int*   pad    = rp + N_NODES + 1;                   // +1 keeps evenness
    int*   cursor = pad + 1;                            // N
    int*   bsum   = cursor + N_NODES;                   // 512
    float* gcat   = (float*)(bsum + 512);               // NG*30
    float* X      = gcat + NG * 30;                     // N*F
    float* H      = X + (long long)N_NODES * F;         // N*F
    int2*  meta   = (int2*)(H + (long long)N_NODES * F);// E int2 (8B aligned: even offset)

    const int zeroN = N_NODES + 3 * NG * F + NG;
    hipLaunchKernelGGL(zero_kernel, dim3((zeroN + 255) / 256), dim3(256), 0, stream, (float*)deg, zeroN);
    hipLaunchKernelGGL(deg_kernel, dim3((N_EDGES + 255) / 256), dim3(256), 0, stream, dst, deg);
    hipLaunchKernelGGL(dinv_kernel, dim3((N_NODES + 255) / 256), dim3(256), 0, stream, deg, dinv);
    hipLaunchKernelGGL(cnt_kernel, dim3((N_NODES + 255) / 256), dim3(256), 0, stream, batch, cnt);
    hipLaunchKernelGGL(scan1_kernel, dim3(NB_SCAN), dim3(256), 0, stream, deg, rp, bsum);
    hipLaunchKernelGGL(scan2_kernel, dim3(1), dim3(512), 0, stream, bsum);
    hipLaunchKernelGGL(scan3_kernel, dim3(NB_SCAN), dim3(256), 0, stream, rp, bsum, cursor);
    hipLaunchKernelGGL(bin_kernel, dim3((N_EDGES + 255) / 256), dim3(256), 0, stream, src, dst, dinv, cursor, meta);

    const int nodeBlocks  = N_NODES / 4;                 // 25000 (aggregate)
    const int gemmBlocks  = (N_NODES + 63) / 64;         // 1563

    // ---- layer 1 ----
    hipLaunchKernelGGL((gemm_kernel<INDIM>), dim3(gemmBlocks), dim3(256), 0, stream, features, W1, H);
    hipLaunchKernelGGL(aggregate_kernel, dim3(nodeBlocks), dim3(256), 0, stream, H, meta, rp, dinv, b1, batch, X, sums + 0 * NG * F);
    // ---- layer 2 ----
    hipLaunchKernelGGL((gemm_kernel<F>), dim3(gemmBlocks), dim3(256), 0, stream, X, W2, H);
    hipLaunchKernelGGL(aggregate_kernel, dim3(nodeBlocks), dim3(256), 0, stream, H, meta, rp, dinv, b2, batch, X, sums + 1 * NG * F);
    // ---- layer 3 ----
    hipLaunchKernelGGL((gemm_kernel<F>), dim3(gemmBlocks), dim3(256), 0, stream, X, W3, H);
    hipLaunchKernelGGL(aggregate_kernel, dim3(nodeBlocks), dim3(256), 0, stream, H, meta, rp, dinv, b3, batch, X, sums + 2 * NG * F);

    // ---- heads + final ----
    hipLaunchKernelGGL(head_kernel, dim3(NG), dim3(32), 0, stream, sums, cnt,
                       Wl1, bl1, Wl2, bl2, Wl3, bl3, gcat);
    hipLaunchKernelGGL(final_kernel, dim3((NG + 255) / 256), dim3(256), 0, stream, gcat, Wf, bf, (float*)d_out);
}

// Round 6
// 518.011 us; speedup vs baseline: 3.3069x; 1.2731x over previous
//
#include <hip/hip_runtime.h>
#include <math.h>

#define N_NODES 100000
#define N_EDGES 1600000
#define INDIM 128
#define F 64
#define ODIM 10
#define NG 512
#define NB_SCAN ((N_NODES + 255) / 256)  // 391

typedef unsigned short ushort_t;
typedef unsigned int uint_t;
typedef __attribute__((ext_vector_type(8))) short bf16x8;
typedef __attribute__((ext_vector_type(4))) float f32x4;

__device__ inline ushort_t f2b(float f) {           // fp32 -> bf16 RNE
    uint_t u = __float_as_uint(f);
    u += 0x7FFF + ((u >> 16) & 1);
    return (ushort_t)(u >> 16);
}
__device__ inline float b2f(ushort_t u) {           // bf16 -> fp32 exact
    return __uint_as_float(((uint_t)u) << 16);
}

// ---------------- utility ----------------
__global__ void zero_kernel(float* p, int n) {
    int i = blockIdx.x * blockDim.x + threadIdx.x;
    if (i < n) p[i] = 0.0f;
}

__global__ void deg_kernel(const int* __restrict__ dst, int* __restrict__ deg) {
    int e = blockIdx.x * blockDim.x + threadIdx.x;
    if (e < N_EDGES) atomicAdd(&deg[dst[e]], 1);
}

__global__ void dinv_kernel(const int* __restrict__ deg, float* __restrict__ dinv) {
    int i = blockIdx.x * blockDim.x + threadIdx.x;
    if (i < N_NODES) dinv[i] = rsqrtf((float)deg[i] + 1.0f);  // +1 self-loop
}

__global__ void cnt_kernel(const int* __restrict__ batch, float* __restrict__ cnt) {
    int i = blockIdx.x * blockDim.x + threadIdx.x;
    if (i < N_NODES) atomicAdd(&cnt[batch[i]], 1.0f);
}

// ---------------- CSR build ----------------
__global__ void scan1_kernel(const int* __restrict__ deg, int* __restrict__ rp,
                             int* __restrict__ bsum) {
    int i = blockIdx.x * 256 + threadIdx.x;
    int v = (i < N_NODES) ? deg[i] : 0;
    int lane = threadIdx.x & 63, w = threadIdx.x >> 6;
    int x = v;
#pragma unroll
    for (int off = 1; off < 64; off <<= 1) {
        int y = __shfl_up(x, off, 64);
        if (lane >= off) x += y;
    }
    __shared__ int wsum[4];
    if (lane == 63) wsum[w] = x;
    __syncthreads();
    int add = 0;
    for (int j = 0; j < w; ++j) add += wsum[j];
    if (i < N_NODES) rp[i] = x - v + add;
    if (threadIdx.x == 255) bsum[blockIdx.x] = x + add;
}

__global__ void scan2_kernel(int* __restrict__ bsum) {
    int i = threadIdx.x;
    int v = (i < NB_SCAN) ? bsum[i] : 0;
    int lane = i & 63, w = i >> 6;
    int x = v;
#pragma unroll
    for (int off = 1; off < 64; off <<= 1) {
        int y = __shfl_up(x, off, 64);
        if (lane >= off) x += y;
    }
    __shared__ int wsum[8];
    if (lane == 63) wsum[w] = x;
    __syncthreads();
    int add = 0;
    for (int j = 0; j < w; ++j) add += wsum[j];
    if (i < NB_SCAN) bsum[i] = x - v + add;
}

__global__ void scan3_kernel(int* __restrict__ rp, const int* __restrict__ bsum,
                             int* __restrict__ cursor) {
    int i = blockIdx.x * 256 + threadIdx.x;
    if (i < N_NODES) {
        int v = rp[i] + bsum[blockIdx.x];
        rp[i] = v;
        cursor[i] = v;
    }
    if (i == 0) rp[N_NODES] = N_EDGES;
}

__global__ void bin_kernel(const int* __restrict__ src, const int* __restrict__ dst,
                           const float* __restrict__ dinv, int* __restrict__ cursor,
                           int2* __restrict__ meta) {
    int e = blockIdx.x * blockDim.x + threadIdx.x;
    if (e >= N_EDGES) return;
    int s = src[e], d = dst[e];
    int pos = atomicAdd(&cursor[d], 1);
    meta[pos] = make_int2(s, __float_as_int(dinv[s] * dinv[d]));
}

// ---------------- casts / packing ----------------
__global__ void castX_kernel(const float* __restrict__ xin, ushort_t* __restrict__ xout, int npairs) {
    int i = blockIdx.x * blockDim.x + threadIdx.x;
    if (i < npairs) {
        float2 v = *(const float2*)&xin[i * 2];
        uint_t p = ((uint_t)f2b(v.x)) | (((uint_t)f2b(v.y)) << 16);
        *(uint_t*)&xout[i * 2] = p;
    }
}

// W [K,64] fp32 -> packed bf16 so each MFMA B-lane reads 16B contiguous:
// Wp[((s*4+g)*64 + n)*8 + j] = W[(s*32 + g*8 + j)*64 + n]
template <int K>
__global__ void packW_kernel(const float* __restrict__ W, ushort_t* __restrict__ Wp) {
    int i = blockIdx.x * 256 + threadIdx.x;
    if (i >= K * 64) return;
    int k = i >> 6, n = i & 63;
    int s = k >> 5, g = (k >> 3) & 3, j = k & 7;
    Wp[(((s * 4 + g) * 64) + n) * 8 + j] = f2b(W[i]);
}

// ---------------- GEMM via MFMA: h = Xb @ W  (bf16 in, bf16 out, fp32 accum) ----------------
// block = 256 thr = 4 waves; wave owns 16 rows x 64 cols; K-steps of 32.
// A: lane(l): row=l&15, k=(l>>4)*8+j (row-major bf16x8 load).
// B: packed so lane reads bf16x8 contiguous. D: col=l&15, row=(l>>4)*4+reg (m89-verified).
template <int K>
__global__ void __launch_bounds__(256) gemm_mfma_kernel(const ushort_t* __restrict__ Xb,
                                                        const ushort_t* __restrict__ Wp,
                                                        ushort_t* __restrict__ h) {
    int lane = threadIdx.x & 63;
    int wv = threadIdx.x >> 6;
    int r = lane & 15, g = lane >> 4;
    int row0 = blockIdx.x * 64 + wv * 16;
    int arow = row0 + r;
    if (arow >= N_NODES) arow = N_NODES - 1;
    const ushort_t* xrow = Xb + (long long)arow * K + g * 8;
    f32x4 acc0 = {0, 0, 0, 0}, acc1 = {0, 0, 0, 0}, acc2 = {0, 0, 0, 0}, acc3 = {0, 0, 0, 0};
#pragma unroll
    for (int s = 0; s < K / 32; ++s) {
        bf16x8 a = *(const bf16x8*)(xrow + s * 32);
        const ushort_t* wb = Wp + (((s * 4 + g) * 64) + r) * 8;
        bf16x8 b0 = *(const bf16x8*)(wb + 0 * 128);
        bf16x8 b1 = *(const bf16x8*)(wb + 1 * 128);
        bf16x8 b2 = *(const bf16x8*)(wb + 2 * 128);
        bf16x8 b3 = *(const bf16x8*)(wb + 3 * 128);
        acc0 = __builtin_amdgcn_mfma_f32_16x16x32_bf16(a, b0, acc0, 0, 0, 0);
        acc1 = __builtin_amdgcn_mfma_f32_16x16x32_bf16(a, b1, acc1, 0, 0, 0);
        acc2 = __builtin_amdgcn_mfma_f32_16x16x32_bf16(a, b2, acc2, 0, 0, 0);
        acc3 = __builtin_amdgcn_mfma_f32_16x16x32_bf16(a, b3, acc3, 0, 0, 0);
    }
#pragma unroll
    for (int q = 0; q < 4; ++q) {
        int rr = row0 + g * 4 + q;
        if (rr < N_NODES) {
            ushort_t* hp = h + (long long)rr * 64 + r;
            hp[0]  = f2b(acc0[q]);
            hp[16] = f2b(acc1[q]);
            hp[32] = f2b(acc2[q]);
            hp[48] = f2b(acc3[q]);
        }
    }
}

// ---------------- fused: selfloop+bias + CSR-gather (bf16) + ReLU + pool ----------------
__global__ void aggregate_kernel(const ushort_t* __restrict__ h, const int2* __restrict__ meta,
                                 const int* __restrict__ rp, const float* __restrict__ dinv,
                                 const float* __restrict__ b, const int* __restrict__ batch,
                                 ushort_t* __restrict__ xout, float* __restrict__ sums) {
    int node = blockIdx.x * 4 + (threadIdx.x >> 6);
    int f = threadIdx.x & 63;
    float di = dinv[node];
    float acc = b[f] + di * di * b2f(h[(long long)node * F + f]);
    int e = rp[node], end = rp[node + 1];
    while (e < end) {
        int cnt = end - e;
        if (cnt > 64) cnt = 64;
        int2 m = make_int2(0, 0);
        if (f < cnt) m = meta[e + f];
        int j = 0;
        for (; j + 16 <= cnt; j += 16) {
            ushort_t hv[16];
#pragma unroll
            for (int c = 0; c < 16; ++c) {
                int s = __shfl(m.x, j + c, 64);
                hv[c] = h[(long long)s * F + f];
            }
#pragma unroll
            for (int c = 0; c < 16; ++c) {
                int wi = __shfl(m.y, j + c, 64);
                acc = fmaf(__int_as_float(wi), b2f(hv[c]), acc);
            }
        }
        for (; j + 4 <= cnt; j += 4) {
            ushort_t hv[4];
#pragma unroll
            for (int c = 0; c < 4; ++c) {
                int s = __shfl(m.x, j + c, 64);
                hv[c] = h[(long long)s * F + f];
            }
#pragma unroll
            for (int c = 0; c < 4; ++c) {
                int wi = __shfl(m.y, j + c, 64);
                acc = fmaf(__int_as_float(wi), b2f(hv[c]), acc);
            }
        }
        for (; j < cnt; ++j) {
            int s = __shfl(m.x, j, 64);
            int wi = __shfl(m.y, j, 64);
            acc = fmaf(__int_as_float(wi), b2f(h[(long long)s * F + f]), acc);
        }
        e += cnt;
    }
    float v = fmaxf(acc, 0.0f);
    if (xout) xout[(long long)node * F + f] = f2b(v);
    atomicAdd(&sums[batch[node] * F + f], v);
}

// ---------------- head + final ----------------
__global__ void head_kernel(const float* __restrict__ sums, const float* __restrict__ cnt,
                            const float* __restrict__ Wl1, const float* __restrict__ bl1,
                            const float* __restrict__ Wl2, const float* __restrict__ bl2,
                            const float* __restrict__ Wl3, const float* __restrict__ bl3,
                            float* __restrict__ gcat) {
    int g = blockIdx.x;
    int t = threadIdx.x;
    if (t >= 30) return;
    int l = t / 10, c = t % 10;
    const float* Wl = (l == 0) ? Wl1 : (l == 1) ? Wl2 : Wl3;
    const float* bl = (l == 0) ? bl1 : (l == 1) ? bl2 : bl3;
    float invc = 1.0f / fmaxf(cnt[g], 1.0f);
    const float* srow = sums + (long long)l * NG * F + (long long)g * F;
    float acc = bl[c];
    for (int k = 0; k < F; ++k) acc += srow[k] * invc * Wl[k * ODIM + c];
    gcat[g * 30 + t] = acc;
}

__global__ void final_kernel(const float* __restrict__ gcat, const float* __restrict__ Wf,
                             const float* __restrict__ bf, float* __restrict__ out) {
    int g = blockIdx.x * blockDim.x + threadIdx.x;
    if (g >= NG) return;
    float z[ODIM];
    float m = -1e30f;
    for (int c = 0; c < ODIM; ++c) {
        float acc = bf[c];
        for (int k = 0; k < 30; ++k) acc += gcat[g * 30 + k] * Wf[k * ODIM + c];
        z[c] = acc;
        m = fmaxf(m, acc);
    }
    float s = 0.0f;
    for (int c = 0; c < ODIM; ++c) { z[c] = expf(z[c] - m); s += z[c]; }
    float inv = 1.0f / s;
    for (int c = 0; c < ODIM; ++c) out[g * ODIM + c] = z[c] * inv;
}

extern "C" void kernel_launch(void* const* d_in, const int* in_sizes, int n_in,
                              void* d_out, int out_size, void* d_ws, size_t ws_size,
                              hipStream_t stream) {
    const float* features = (const float*)d_in[0];
    const int*   edge     = (const int*)d_in[1];
    const int*   batch    = (const int*)d_in[2];
    const float* W1 = (const float*)d_in[3];
    const float* b1 = (const float*)d_in[4];
    const float* W2 = (const float*)d_in[5];
    const float* b2 = (const float*)d_in[6];
    const float* W3 = (const float*)d_in[7];
    const float* b3 = (const float*)d_in[8];
    const float* Wl1 = (const float*)d_in[9];
    const float* bl1 = (const float*)d_in[10];
    const float* Wl2 = (const float*)d_in[11];
    const float* bl2 = (const float*)d_in[12];
    const float* Wl3 = (const float*)d_in[13];
    const float* bl3 = (const float*)d_in[14];
    const float* Wf = (const float*)d_in[15];
    const float* bf = (const float*)d_in[16];

    const int* src = edge;
    const int* dst = edge + N_EDGES;

    // ---- workspace layout (256B-aligned slabs) ----
    char* p = (char*)d_ws;
    auto alloc = [&](size_t bytes) -> char* {
        char* q = p;
        p += (bytes + 255) & ~(size_t)255;
        return q;
    };
    int*      deg   = (int*)alloc(N_NODES * 4);
    float*    sums  = (float*)alloc(3 * NG * F * 4);
    float*    cnt   = (float*)alloc(NG * 4);
    float*    dinv  = (float*)alloc(N_NODES * 4);
    int*      rp    = (int*)alloc((N_NODES + 1) * 4);
    int*      cursor= (int*)alloc(N_NODES * 4);
    int*      bsum  = (int*)alloc(512 * 4);
    float*    gcat  = (float*)alloc(NG * 30 * 4);
    ushort_t* Xb0   = (ushort_t*)alloc((size_t)N_NODES * INDIM * 2);
    ushort_t* X     = (ushort_t*)alloc((size_t)N_NODES * F * 2);
    ushort_t* H     = (ushort_t*)alloc((size_t)N_NODES * F * 2);
    int2*     meta  = (int2*)alloc((size_t)N_EDGES * 8);
    ushort_t* Wp1   = (ushort_t*)alloc(INDIM * 64 * 2);
    ushort_t* Wp2   = (ushort_t*)alloc(F * 64 * 2);
    ushort_t* Wp3   = (ushort_t*)alloc(F * 64 * 2);

    // zero [deg .. cnt] span (contiguous slabs incl. padding)
    const int zeroN = (int)(((char*)(cnt + NG) - (char*)deg) / 4);
    hipLaunchKernelGGL(zero_kernel, dim3((zeroN + 255) / 256), dim3(256), 0, stream, (float*)deg, zeroN);
    hipLaunchKernelGGL(deg_kernel, dim3((N_EDGES + 255) / 256), dim3(256), 0, stream, dst, deg);
    hipLaunchKernelGGL(dinv_kernel, dim3((N_NODES + 255) / 256), dim3(256), 0, stream, deg, dinv);
    hipLaunchKernelGGL(cnt_kernel, dim3((N_NODES + 255) / 256), dim3(256), 0, stream, batch, cnt);
    hipLaunchKernelGGL(scan1_kernel, dim3(NB_SCAN), dim3(256), 0, stream, deg, rp, bsum);
    hipLaunchKernelGGL(scan2_kernel, dim3(1), dim3(512), 0, stream, bsum);
    hipLaunchKernelGGL(scan3_kernel, dim3(NB_SCAN), dim3(256), 0, stream, rp, bsum, cursor);
    hipLaunchKernelGGL(bin_kernel, dim3((N_EDGES + 255) / 256), dim3(256), 0, stream, src, dst, dinv, cursor, meta);

    // casts / packs
    hipLaunchKernelGGL(castX_kernel, dim3((N_NODES * INDIM / 2 + 255) / 256), dim3(256), 0, stream,
                       features, Xb0, N_NODES * INDIM / 2);
    hipLaunchKernelGGL((packW_kernel<INDIM>), dim3((INDIM * 64 + 255) / 256), dim3(256), 0, stream, W1, Wp1);
    hipLaunchKernelGGL((packW_kernel<F>), dim3((F * 64 + 255) / 256), dim3(256), 0, stream, W2, Wp2);
    hipLaunchKernelGGL((packW_kernel<F>), dim3((F * 64 + 255) / 256), dim3(256), 0, stream, W3, Wp3);

    const int nodeBlocks = N_NODES / 4;          // 25000 (aggregate)
    const int gemmBlocks = (N_NODES + 63) / 64;  // 1563

    // ---- layer 1 ----
    hipLaunchKernelGGL((gemm_mfma_kernel<INDIM>), dim3(gemmBlocks), dim3(256), 0, stream, Xb0, Wp1, H);
    hipLaunchKernelGGL(aggregate_kernel, dim3(nodeBlocks), dim3(256), 0, stream, H, meta, rp, dinv, b1, batch, X, sums + 0 * NG * F);
    // ---- layer 2 ----
    hipLaunchKernelGGL((gemm_mfma_kernel<F>), dim3(gemmBlocks), dim3(256), 0, stream, X, Wp2, H);
    hipLaunchKernelGGL(aggregate_kernel, dim3(nodeBlocks), dim3(256), 0, stream, H, meta, rp, dinv, b2, batch, X, sums + 1 * NG * F);
    // ---- layer 3 (no X store needed; pool only) ----
    hipLaunchKernelGGL((gemm_mfma_kernel<F>), dim3(gemmBlocks), dim3(256), 0, stream, X, Wp3, H);
    hipLaunchKernelGGL(aggregate_kernel, dim3(nodeBlocks), dim3(256), 0, stream, H, meta, rp, dinv, b3, batch, (ushort_t*)nullptr, sums + 2 * NG * F);

    // ---- heads + final ----
    hipLaunchKernelGGL(head_kernel, dim3(NG), dim3(32), 0, stream, sums, cnt,
                       Wl1, bl1, Wl2, bl2, Wl3, bl3, gcat);
    hipLaunchKernelGGL(final_kernel, dim3((NG + 255) / 256), dim3(256), 0, stream, gcat, Wf, bf, (float*)d_out);
}

// Round 7
// 438.671 us; speedup vs baseline: 3.9050x; 1.1809x over previous
//
#include <hip/hip_runtime.h>
#include <math.h>

#define N_NODES 100000
#define N_EDGES 1600000
#define INDIM 128
#define F 64
#define ODIM 10
#define NG 512
#define NB_SCAN ((N_NODES + 255) / 256)  // 391

typedef unsigned short ushort_t;
typedef unsigned int uint_t;
typedef __attribute__((ext_vector_type(8))) short bf16x8;
typedef __attribute__((ext_vector_type(4))) float f32x4;

__device__ inline ushort_t f2b(float f) {           // fp32 -> bf16 RNE
    uint_t u = __float_as_uint(f);
    u += 0x7FFF + ((u >> 16) & 1);
    return (ushort_t)(u >> 16);
}
__device__ inline float b2f(ushort_t u) {           // bf16 -> fp32 exact
    return __uint_as_float(((uint_t)u) << 16);
}

// ---------------- utility ----------------
__global__ void zero_kernel(float* p, int n) {
    int i = blockIdx.x * blockDim.x + threadIdx.x;
    if (i < n) p[i] = 0.0f;
}

__global__ void deg_kernel(const int* __restrict__ dst, int* __restrict__ deg) {
    int e = blockIdx.x * blockDim.x + threadIdx.x;
    if (e < N_EDGES) atomicAdd(&deg[dst[e]], 1);
}

__global__ void dinv_kernel(const int* __restrict__ deg, float* __restrict__ dinv) {
    int i = blockIdx.x * blockDim.x + threadIdx.x;
    if (i < N_NODES) dinv[i] = rsqrtf((float)deg[i] + 1.0f);  // +1 self-loop
}

// batch is SORTED -> per-graph count = upper_bound - lower_bound (no atomics)
__global__ void cnt_bs_kernel(const int* __restrict__ batch, float* __restrict__ cnt) {
    int g = blockIdx.x * blockDim.x + threadIdx.x;
    if (g >= NG) return;
    int lo = 0, hi = N_NODES;
    while (lo < hi) { int mid = (lo + hi) >> 1; if (batch[mid] < g) lo = mid + 1; else hi = mid; }
    int start = lo;
    lo = 0; hi = N_NODES;
    while (lo < hi) { int mid = (lo + hi) >> 1; if (batch[mid] <= g) lo = mid + 1; else hi = mid; }
    cnt[g] = (float)(lo - start);
}

// ---------------- CSR build ----------------
__global__ void scan1_kernel(const int* __restrict__ deg, int* __restrict__ rp,
                             int* __restrict__ bsum) {
    int i = blockIdx.x * 256 + threadIdx.x;
    int v = (i < N_NODES) ? deg[i] : 0;
    int lane = threadIdx.x & 63, w = threadIdx.x >> 6;
    int x = v;
#pragma unroll
    for (int off = 1; off < 64; off <<= 1) {
        int y = __shfl_up(x, off, 64);
        if (lane >= off) x += y;
    }
    __shared__ int wsum[4];
    if (lane == 63) wsum[w] = x;
    __syncthreads();
    int add = 0;
    for (int j = 0; j < w; ++j) add += wsum[j];
    if (i < N_NODES) rp[i] = x - v + add;
    if (threadIdx.x == 255) bsum[blockIdx.x] = x + add;
}

__global__ void scan2_kernel(int* __restrict__ bsum) {
    int i = threadIdx.x;
    int v = (i < NB_SCAN) ? bsum[i] : 0;
    int lane = i & 63, w = i >> 6;
    int x = v;
#pragma unroll
    for (int off = 1; off < 64; off <<= 1) {
        int y = __shfl_up(x, off, 64);
        if (lane >= off) x += y;
    }
    __shared__ int wsum[8];
    if (lane == 63) wsum[w] = x;
    __syncthreads();
    int add = 0;
    for (int j = 0; j < w; ++j) add += wsum[j];
    if (i < NB_SCAN) bsum[i] = x - v + add;
}

__global__ void scan3_kernel(int* __restrict__ rp, const int* __restrict__ bsum,
                             int* __restrict__ cursor) {
    int i = blockIdx.x * 256 + threadIdx.x;
    if (i < N_NODES) {
        int v = rp[i] + bsum[blockIdx.x];
        rp[i] = v;
        cursor[i] = v;
    }
    if (i == 0) rp[N_NODES] = N_EDGES;
}

__global__ void bin_kernel(const int* __restrict__ src, const int* __restrict__ dst,
                           const float* __restrict__ dinv, int* __restrict__ cursor,
                           int2* __restrict__ meta) {
    int e = blockIdx.x * blockDim.x + threadIdx.x;
    if (e >= N_EDGES) return;
    int s = src[e], d = dst[e];
    int pos = atomicAdd(&cursor[d], 1);
    meta[pos] = make_int2(s, __float_as_int(dinv[s] * dinv[d]));
}

// ---------------- casts / packing ----------------
__global__ void castX_kernel(const float* __restrict__ xin, ushort_t* __restrict__ xout, int npairs) {
    int i = blockIdx.x * blockDim.x + threadIdx.x;
    if (i < npairs) {
        float2 v = *(const float2*)&xin[i * 2];
        uint_t p = ((uint_t)f2b(v.x)) | (((uint_t)f2b(v.y)) << 16);
        *(uint_t*)&xout[i * 2] = p;
    }
}

// W [K,64] fp32 -> packed bf16 so each MFMA B-lane reads 16B contiguous:
// Wp[((s*4+g)*64 + n)*8 + j] = W[(s*32 + g*8 + j)*64 + n]
template <int K>
__global__ void packW_kernel(const float* __restrict__ W, ushort_t* __restrict__ Wp) {
    int i = blockIdx.x * 256 + threadIdx.x;
    if (i >= K * 64) return;
    int k = i >> 6, n = i & 63;
    int s = k >> 5, g = (k >> 3) & 3, j = k & 7;
    Wp[(((s * 4 + g) * 64) + n) * 8 + j] = f2b(W[i]);
}

// ---------------- GEMM via MFMA: h = Xb @ W  (bf16 in, bf16 out, fp32 accum) ----------------
template <int K>
__global__ void __launch_bounds__(256) gemm_mfma_kernel(const ushort_t* __restrict__ Xb,
                                                        const ushort_t* __restrict__ Wp,
                                                        ushort_t* __restrict__ h) {
    int lane = threadIdx.x & 63;
    int wv = threadIdx.x >> 6;
    int r = lane & 15, g = lane >> 4;
    int row0 = blockIdx.x * 64 + wv * 16;
    int arow = row0 + r;
    if (arow >= N_NODES) arow = N_NODES - 1;
    const ushort_t* xrow = Xb + (long long)arow * K + g * 8;
    f32x4 acc0 = {0, 0, 0, 0}, acc1 = {0, 0, 0, 0}, acc2 = {0, 0, 0, 0}, acc3 = {0, 0, 0, 0};
#pragma unroll
    for (int s = 0; s < K / 32; ++s) {
        bf16x8 a = *(const bf16x8*)(xrow + s * 32);
        const ushort_t* wb = Wp + (((s * 4 + g) * 64) + r) * 8;
        bf16x8 b0 = *(const bf16x8*)(wb + 0 * 128);
        bf16x8 b1 = *(const bf16x8*)(wb + 1 * 128);
        bf16x8 b2 = *(const bf16x8*)(wb + 2 * 128);
        bf16x8 b3 = *(const bf16x8*)(wb + 3 * 128);
        acc0 = __builtin_amdgcn_mfma_f32_16x16x32_bf16(a, b0, acc0, 0, 0, 0);
        acc1 = __builtin_amdgcn_mfma_f32_16x16x32_bf16(a, b1, acc1, 0, 0, 0);
        acc2 = __builtin_amdgcn_mfma_f32_16x16x32_bf16(a, b2, acc2, 0, 0, 0);
        acc3 = __builtin_amdgcn_mfma_f32_16x16x32_bf16(a, b3, acc3, 0, 0, 0);
    }
#pragma unroll
    for (int q = 0; q < 4; ++q) {
        int rr = row0 + g * 4 + q;
        if (rr < N_NODES) {
            ushort_t* hp = h + (long long)rr * 64 + r;
            hp[0]  = f2b(acc0[q]);
            hp[16] = f2b(acc1[q]);
            hp[32] = f2b(acc2[q]);
            hp[48] = f2b(acc3[q]);
        }
    }
}

// ---------------- fused: selfloop+bias + CSR-gather (bf16) + ReLU + pool ----------------
__global__ void aggregate_kernel(const ushort_t* __restrict__ h, const int2* __restrict__ meta,
                                 const int* __restrict__ rp, const float* __restrict__ dinv,
                                 const float* __restrict__ b, const int* __restrict__ batch,
                                 ushort_t* __restrict__ xout, float* __restrict__ sums) {
    int node = blockIdx.x * 4 + (threadIdx.x >> 6);
    int f = threadIdx.x & 63;
    float di = dinv[node];
    float acc = b[f] + di * di * b2f(h[(long long)node * F + f]);
    int e = rp[node], end = rp[node + 1];
    while (e < end) {
        int cnt = end - e;
        if (cnt > 64) cnt = 64;
        int2 m = make_int2(0, 0);
        if (f < cnt) m = meta[e + f];
        int j = 0;
        for (; j + 16 <= cnt; j += 16) {
            ushort_t hv[16];
#pragma unroll
            for (int c = 0; c < 16; ++c) {
                int s = __shfl(m.x, j + c, 64);
                hv[c] = h[(long long)s * F + f];
            }
#pragma unroll
            for (int c = 0; c < 16; ++c) {
                int wi = __shfl(m.y, j + c, 64);
                acc = fmaf(__int_as_float(wi), b2f(hv[c]), acc);
            }
        }
        for (; j + 4 <= cnt; j += 4) {
            ushort_t hv[4];
#pragma unroll
            for (int c = 0; c < 4; ++c) {
                int s = __shfl(m.x, j + c, 64);
                hv[c] = h[(long long)s * F + f];
            }
#pragma unroll
            for (int c = 0; c < 4; ++c) {
                int wi = __shfl(m.y, j + c, 64);
                acc = fmaf(__int_as_float(wi), b2f(hv[c]), acc);
            }
        }
        for (; j < cnt; ++j) {
            int s = __shfl(m.x, j, 64);
            int wi = __shfl(m.y, j, 64);
            acc = fmaf(__int_as_float(wi), b2f(h[(long long)s * F + f]), acc);
        }
        e += cnt;
    }
    float v = fmaxf(acc, 0.0f);
    if (xout) xout[(long long)node * F + f] = f2b(v);
    atomicAdd(&sums[batch[node] * F + f], v);
}

// ---------------- head + final ----------------
__global__ void head_kernel(const float* __restrict__ sums, const float* __restrict__ cnt,
                            const float* __restrict__ Wl1, const float* __restrict__ bl1,
                            const float* __restrict__ Wl2, const float* __restrict__ bl2,
                            const float* __restrict__ Wl3, const float* __restrict__ bl3,
                            float* __restrict__ gcat) {
    int g = blockIdx.x;
    int t = threadIdx.x;
    if (t >= 30) return;
    int l = t / 10, c = t % 10;
    const float* Wl = (l == 0) ? Wl1 : (l == 1) ? Wl2 : Wl3;
    const float* bl = (l == 0) ? bl1 : (l == 1) ? bl2 : bl3;
    float invc = 1.0f / fmaxf(cnt[g], 1.0f);
    const float* srow = sums + (long long)l * NG * F + (long long)g * F;
    float acc = bl[c];
    for (int k = 0; k < F; ++k) acc += srow[k] * invc * Wl[k * ODIM + c];
    gcat[g * 30 + t] = acc;
}

__global__ void final_kernel(const float* __restrict__ gcat, const float* __restrict__ Wf,
                             const float* __restrict__ bf, float* __restrict__ out) {
    int g = blockIdx.x * blockDim.x + threadIdx.x;
    if (g >= NG) return;
    float z[ODIM];
    float m = -1e30f;
    for (int c = 0; c < ODIM; ++c) {
        float acc = bf[c];
        for (int k = 0; k < 30; ++k) acc += gcat[g * 30 + k] * Wf[k * ODIM + c];
        z[c] = acc;
        m = fmaxf(m, acc);
    }
    float s = 0.0f;
    for (int c = 0; c < ODIM; ++c) { z[c] = expf(z[c] - m); s += z[c]; }
    float inv = 1.0f / s;
    for (int c = 0; c < ODIM; ++c) out[g * ODIM + c] = z[c] * inv;
}

extern "C" void kernel_launch(void* const* d_in, const int* in_sizes, int n_in,
                              void* d_out, int out_size, void* d_ws, size_t ws_size,
                              hipStream_t stream) {
    const float* features = (const float*)d_in[0];
    const int*   edge     = (const int*)d_in[1];
    const int*   batch    = (const int*)d_in[2];
    const float* W1 = (const float*)d_in[3];
    const float* b1 = (const float*)d_in[4];
    const float* W2 = (const float*)d_in[5];
    const float* b2 = (const float*)d_in[6];
    const float* W3 = (const float*)d_in[7];
    const float* b3 = (const float*)d_in[8];
    const float* Wl1 = (const float*)d_in[9];
    const float* bl1 = (const float*)d_in[10];
    const float* Wl2 = (const float*)d_in[11];
    const float* bl2 = (const float*)d_in[12];
    const float* Wl3 = (const float*)d_in[13];
    const float* bl3 = (const float*)d_in[14];
    const float* Wf = (const float*)d_in[15];
    const float* bf = (const float*)d_in[16];

    const int* src = edge;
    const int* dst = edge + N_EDGES;

    // ---- workspace layout (256B-aligned slabs) ----
    char* p = (char*)d_ws;
    auto alloc = [&](size_t bytes) -> char* {
        char* q = p;
        p += (bytes + 255) & ~(size_t)255;
        return q;
    };
    int*      deg   = (int*)alloc(N_NODES * 4);
    float*    sums  = (float*)alloc(3 * NG * F * 4);
    float*    cnt   = (float*)alloc(NG * 4);
    float*    dinv  = (float*)alloc(N_NODES * 4);
    int*      rp    = (int*)alloc((N_NODES + 1) * 4);
    int*      cursor= (int*)alloc(N_NODES * 4);
    int*      bsum  = (int*)alloc(512 * 4);
    float*    gcat  = (float*)alloc(NG * 30 * 4);
    ushort_t* Xb0   = (ushort_t*)alloc((size_t)N_NODES * INDIM * 2);
    ushort_t* X     = (ushort_t*)alloc((size_t)N_NODES * F * 2);
    ushort_t* H     = (ushort_t*)alloc((size_t)N_NODES * F * 2);
    int2*     meta  = (int2*)alloc((size_t)N_EDGES * 8);
    ushort_t* Wp1   = (ushort_t*)alloc(INDIM * 64 * 2);
    ushort_t* Wp2   = (ushort_t*)alloc(F * 64 * 2);
    ushort_t* Wp3   = (ushort_t*)alloc(F * 64 * 2);

    // zero [deg | sums] (contiguous slabs)
    const int zeroN = (int)(((char*)(sums + 3 * NG * F) - (char*)deg) / 4);
    hipLaunchKernelGGL(zero_kernel, dim3((zeroN + 255) / 256), dim3(256), 0, stream, (float*)deg, zeroN);
    hipLaunchKernelGGL(deg_kernel, dim3((N_EDGES + 255) / 256), dim3(256), 0, stream, dst, deg);
    hipLaunchKernelGGL(dinv_kernel, dim3((N_NODES + 255) / 256), dim3(256), 0, stream, deg, dinv);
    hipLaunchKernelGGL(cnt_bs_kernel, dim3((NG + 255) / 256), dim3(256), 0, stream, batch, cnt);
    hipLaunchKernelGGL(scan1_kernel, dim3(NB_SCAN), dim3(256), 0, stream, deg, rp, bsum);
    hipLaunchKernelGGL(scan2_kernel, dim3(1), dim3(512), 0, stream, bsum);
    hipLaunchKernelGGL(scan3_kernel, dim3(NB_SCAN), dim3(256), 0, stream, rp, bsum, cursor);
    hipLaunchKernelGGL(bin_kernel, dim3((N_EDGES + 255) / 256), dim3(256), 0, stream, src, dst, dinv, cursor, meta);

    // casts / packs
    hipLaunchKernelGGL(castX_kernel, dim3((N_NODES * INDIM / 2 + 255) / 256), dim3(256), 0, stream,
                       features, Xb0, N_NODES * INDIM / 2);
    hipLaunchKernelGGL((packW_kernel<INDIM>), dim3((INDIM * 64 + 255) / 256), dim3(256), 0, stream, W1, Wp1);
    hipLaunchKernelGGL((packW_kernel<F>), dim3((F * 64 + 255) / 256), dim3(256), 0, stream, W2, Wp2);
    hipLaunchKernelGGL((packW_kernel<F>), dim3((F * 64 + 255) / 256), dim3(256), 0, stream, W3, Wp3);

    const int nodeBlocks = N_NODES / 4;          // 25000 (aggregate)
    const int gemmBlocks = (N_NODES + 63) / 64;  // 1563

    // ---- layer 1 ----
    hipLaunchKernelGGL((gemm_mfma_kernel<INDIM>), dim3(gemmBlocks), dim3(256), 0, stream, Xb0, Wp1, H);
    hipLaunchKernelGGL(aggregate_kernel, dim3(nodeBlocks), dim3(256), 0, stream, H, meta, rp, dinv, b1, batch, X, sums + 0 * NG * F);
    // ---- layer 2 ----
    hipLaunchKernelGGL((gemm_mfma_kernel<F>), dim3(gemmBlocks), dim3(256), 0, stream, X, Wp2, H);
    hipLaunchKernelGGL(aggregate_kernel, dim3(nodeBlocks), dim3(256), 0, stream, H, meta, rp, dinv, b2, batch, X, sums + 1 * NG * F);
    // ---- layer 3 (no X store needed; pool only) ----
    hipLaunchKernelGGL((gemm_mfma_kernel<F>), dim3(gemmBlocks), dim3(256), 0, stream, X, Wp3, H);
    hipLaunchKernelGGL(aggregate_kernel, dim3(nodeBlocks), dim3(256), 0, stream, H, meta, rp, dinv, b3, batch, (ushort_t*)nullptr, sums + 2 * NG * F);

    // ---- heads + final ----
    hipLaunchKernelGGL(head_kernel, dim3(NG), dim3(32), 0, stream, sums, cnt,
                       Wl1, bl1, Wl2, bl2, Wl3, bl3, gcat);
    hipLaunchKernelGGL(final_kernel, dim3((NG + 255) / 256), dim3(256), 0, stream, gcat, Wf, bf, (float*)d_out);
}

// Round 8
// 417.380 us; speedup vs baseline: 4.1041x; 1.0510x over previous
//
#include <hip/hip_runtime.h>
#include <math.h>

#define N_NODES 100000
#define N_EDGES 1600000
#define INDIM 128
#define F 64
#define ODIM 10
#define NG 512
#define NB_SCAN ((N_NODES + 255) / 256)  // 391
#define PSZ 12500                        // dst-partition size (N_NODES/8)
#define BIN_BLOCKS 2048                  // 8 groups x 256 blocks

typedef unsigned short ushort_t;
typedef unsigned int uint_t;
typedef __attribute__((ext_vector_type(8))) short bf16x8;
typedef __attribute__((ext_vector_type(4))) float f32x4;

__device__ inline ushort_t f2b(float f) {           // fp32 -> bf16 RNE
    uint_t u = __float_as_uint(f);
    u += 0x7FFF + ((u >> 16) & 1);
    return (ushort_t)(u >> 16);
}
__device__ inline float b2f(ushort_t u) {           // bf16 -> fp32 exact
    return __uint_as_float(((uint_t)u) << 16);
}

// ---------------- utility ----------------
__global__ void zero_kernel(float* p, int n) {
    int i = blockIdx.x * blockDim.x + threadIdx.x;
    if (i < n) p[i] = 0.0f;
}

__global__ void deg_kernel(const int* __restrict__ dst, int* __restrict__ deg) {
    int e = blockIdx.x * blockDim.x + threadIdx.x;
    if (e < N_EDGES) atomicAdd(&deg[dst[e]], 1);
}

__global__ void dinv_kernel(const int* __restrict__ deg, float* __restrict__ dinv) {
    int i = blockIdx.x * blockDim.x + threadIdx.x;
    if (i < N_NODES) dinv[i] = rsqrtf((float)deg[i] + 1.0f);  // +1 self-loop
}

// batch is SORTED -> per-graph count = upper_bound - lower_bound (no atomics)
__global__ void cnt_bs_kernel(const int* __restrict__ batch, float* __restrict__ cnt) {
    int g = blockIdx.x * blockDim.x + threadIdx.x;
    if (g >= NG) return;
    int lo = 0, hi = N_NODES;
    while (lo < hi) { int mid = (lo + hi) >> 1; if (batch[mid] < g) lo = mid + 1; else hi = mid; }
    int start = lo;
    lo = 0; hi = N_NODES;
    while (lo < hi) { int mid = (lo + hi) >> 1; if (batch[mid] <= g) lo = mid + 1; else hi = mid; }
    cnt[g] = (float)(lo - start);
}

// ---------------- CSR build ----------------
__global__ void scan1_kernel(const int* __restrict__ deg, int* __restrict__ rp,
                             int* __restrict__ bsum) {
    int i = blockIdx.x * 256 + threadIdx.x;
    int v = (i < N_NODES) ? deg[i] : 0;
    int lane = threadIdx.x & 63, w = threadIdx.x >> 6;
    int x = v;
#pragma unroll
    for (int off = 1; off < 64; off <<= 1) {
        int y = __shfl_up(x, off, 64);
        if (lane >= off) x += y;
    }
    __shared__ int wsum[4];
    if (lane == 63) wsum[w] = x;
    __syncthreads();
    int add = 0;
    for (int j = 0; j < w; ++j) add += wsum[j];
    if (i < N_NODES) rp[i] = x - v + add;
    if (threadIdx.x == 255) bsum[blockIdx.x] = x + add;
}

__global__ void scan2_kernel(int* __restrict__ bsum) {
    int i = threadIdx.x;
    int v = (i < NB_SCAN) ? bsum[i] : 0;
    int lane = i & 63, w = i >> 6;
    int x = v;
#pragma unroll
    for (int off = 1; off < 64; off <<= 1) {
        int y = __shfl_up(x, off, 64);
        if (lane >= off) x += y;
    }
    __shared__ int wsum[8];
    if (lane == 63) wsum[w] = x;
    __syncthreads();
    int add = 0;
    for (int j = 0; j < w; ++j) add += wsum[j];
    if (i < NB_SCAN) bsum[i] = x - v + add;
}

__global__ void scan3_kernel(int* __restrict__ rp, const int* __restrict__ bsum,
                             int* __restrict__ cursor) {
    int i = blockIdx.x * 256 + threadIdx.x;
    if (i < N_NODES) {
        int v = rp[i] + bsum[blockIdx.x];
        rp[i] = v;
        cursor[i] = v;
    }
    if (i == 0) rp[N_NODES] = N_EDGES;
}

// XCD-partitioned binning: group g (= blockIdx&7, round-robin XCD heuristic)
// bins only edges with dst in [g*PSZ, (g+1)*PSZ). Meta region per group ~1.6MB
// stays in ONE XCD's L2 -> full-line writebacks (kills the 8x write amp).
// Correctness does not depend on the XCD mapping (positions unique via atomics).
__global__ void bin_part_kernel(const int* __restrict__ src, const int* __restrict__ dst,
                                const float* __restrict__ dinv, int* __restrict__ cursor,
                                int2* __restrict__ meta) {
    int grp = blockIdx.x & 7;
    int gidx = blockIdx.x >> 3;
    int lo = grp * PSZ, hi = lo + PSZ;
    const int stride = (BIN_BLOCKS / 8) * 256;
    for (int e = gidx * 256 + threadIdx.x; e < N_EDGES; e += stride) {
        int d = dst[e];
        if (d < lo || d >= hi) continue;
        int s = src[e];
        int pos = atomicAdd(&cursor[d], 1);
        meta[pos] = make_int2(s, __float_as_int(dinv[s] * dinv[d]));
    }
}

// ---------------- packing ----------------
// W [K,64] fp32 -> packed bf16 so each MFMA B-lane reads 16B contiguous:
// Wp[((s*4+g)*64 + n)*8 + j] = W[(s*32 + g*8 + j)*64 + n]
template <int K>
__global__ void packW_kernel(const float* __restrict__ W, ushort_t* __restrict__ Wp) {
    int i = blockIdx.x * 256 + threadIdx.x;
    if (i >= K * 64) return;
    int k = i >> 6, n = i & 63;
    int s = k >> 5, g = (k >> 3) & 3, j = k & 7;
    Wp[(((s * 4 + g) * 64) + n) * 8 + j] = f2b(W[i]);
}

// ---------------- GEMM via MFMA: h = X @ W  (bf16 or fp32 A, bf16 out, fp32 accum) ----------------
template <int K, bool A32>
__global__ void __launch_bounds__(256) gemm_mfma_kernel(const void* __restrict__ Xp,
                                                        const ushort_t* __restrict__ Wp,
                                                        ushort_t* __restrict__ h) {
    int lane = threadIdx.x & 63;
    int wv = threadIdx.x >> 6;
    int r = lane & 15, g = lane >> 4;
    int row0 = blockIdx.x * 64 + wv * 16;
    int arow = row0 + r;
    if (arow >= N_NODES) arow = N_NODES - 1;
    f32x4 acc0 = {0, 0, 0, 0}, acc1 = {0, 0, 0, 0}, acc2 = {0, 0, 0, 0}, acc3 = {0, 0, 0, 0};
#pragma unroll
    for (int s = 0; s < K / 32; ++s) {
        bf16x8 a;
        if constexpr (A32) {
            const float* xrow = (const float*)Xp + (long long)arow * K + g * 8 + s * 32;
            float4 xa = *(const float4*)xrow;
            float4 xb = *(const float4*)(xrow + 4);
            a[0] = (short)f2b(xa.x); a[1] = (short)f2b(xa.y);
            a[2] = (short)f2b(xa.z); a[3] = (short)f2b(xa.w);
            a[4] = (short)f2b(xb.x); a[5] = (short)f2b(xb.y);
            a[6] = (short)f2b(xb.z); a[7] = (short)f2b(xb.w);
        } else {
            const ushort_t* xrow = (const ushort_t*)Xp + (long long)arow * K + g * 8 + s * 32;
            a = *(const bf16x8*)xrow;
        }
        const ushort_t* wb = Wp + (((s * 4 + g) * 64) + r) * 8;
        bf16x8 b0 = *(const bf16x8*)(wb + 0 * 128);
        bf16x8 b1 = *(const bf16x8*)(wb + 1 * 128);
        bf16x8 b2 = *(const bf16x8*)(wb + 2 * 128);
        bf16x8 b3 = *(const bf16x8*)(wb + 3 * 128);
        acc0 = __builtin_amdgcn_mfma_f32_16x16x32_bf16(a, b0, acc0, 0, 0, 0);
        acc1 = __builtin_amdgcn_mfma_f32_16x16x32_bf16(a, b1, acc1, 0, 0, 0);
        acc2 = __builtin_amdgcn_mfma_f32_16x16x32_bf16(a, b2, acc2, 0, 0, 0);
        acc3 = __builtin_amdgcn_mfma_f32_16x16x32_bf16(a, b3, acc3, 0, 0, 0);
    }
#pragma unroll
    for (int q = 0; q < 4; ++q) {
        int rr = row0 + g * 4 + q;
        if (rr < N_NODES) {
            ushort_t* hp = h + (long long)rr * 64 + r;
            hp[0]  = f2b(acc0[q]);
            hp[16] = f2b(acc1[q]);
            hp[32] = f2b(acc2[q]);
            hp[48] = f2b(acc3[q]);
        }
    }
}

// ---------------- fused: selfloop+bias + CSR-gather (bf16) + ReLU + pool ----------------
__global__ void aggregate_kernel(const ushort_t* __restrict__ h, const int2* __restrict__ meta,
                                 const int* __restrict__ rp, const float* __restrict__ dinv,
                                 const float* __restrict__ b, const int* __restrict__ batch,
                                 ushort_t* __restrict__ xout, float* __restrict__ sums) {
    int node = blockIdx.x * 4 + (threadIdx.x >> 6);
    int f = threadIdx.x & 63;
    float di = dinv[node];
    float acc = b[f] + di * di * b2f(h[(long long)node * F + f]);
    int e = rp[node], end = rp[node + 1];
    while (e < end) {
        int cnt = end - e;
        if (cnt > 64) cnt = 64;
        int2 m = make_int2(0, 0);
        if (f < cnt) m = meta[e + f];
        int j = 0;
        for (; j + 16 <= cnt; j += 16) {
            ushort_t hv[16];
#pragma unroll
            for (int c = 0; c < 16; ++c) {
                int s = __shfl(m.x, j + c, 64);
                hv[c] = h[(long long)s * F + f];
            }
#pragma unroll
            for (int c = 0; c < 16; ++c) {
                int wi = __shfl(m.y, j + c, 64);
                acc = fmaf(__int_as_float(wi), b2f(hv[c]), acc);
            }
        }
        for (; j + 4 <= cnt; j += 4) {
            ushort_t hv[4];
#pragma unroll
            for (int c = 0; c < 4; ++c) {
                int s = __shfl(m.x, j + c, 64);
                hv[c] = h[(long long)s * F + f];
            }
#pragma unroll
            for (int c = 0; c < 4; ++c) {
                int wi = __shfl(m.y, j + c, 64);
                acc = fmaf(__int_as_float(wi), b2f(hv[c]), acc);
            }
        }
        for (; j < cnt; ++j) {
            int s = __shfl(m.x, j, 64);
            int wi = __shfl(m.y, j, 64);
            acc = fmaf(__int_as_float(wi), b2f(h[(long long)s * F + f]), acc);
        }
        e += cnt;
    }
    float v = fmaxf(acc, 0.0f);
    if (xout) xout[(long long)node * F + f] = f2b(v);
    atomicAdd(&sums[batch[node] * F + f], v);
}

// ---------------- head + final ----------------
__global__ void head_kernel(const float* __restrict__ sums, const float* __restrict__ cnt,
                            const float* __restrict__ Wl1, const float* __restrict__ bl1,
                            const float* __restrict__ Wl2, const float* __restrict__ bl2,
                            const float* __restrict__ Wl3, const float* __restrict__ bl3,
                            float* __restrict__ gcat) {
    int g = blockIdx.x;
    int t = threadIdx.x;
    if (t >= 30) return;
    int l = t / 10, c = t % 10;
    const float* Wl = (l == 0) ? Wl1 : (l == 1) ? Wl2 : Wl3;
    const float* bl = (l == 0) ? bl1 : (l == 1) ? bl2 : bl3;
    float invc = 1.0f / fmaxf(cnt[g], 1.0f);
    const float* srow = sums + (long long)l * NG * F + (long long)g * F;
    float acc = bl[c];
    for (int k = 0; k < F; ++k) acc += srow[k] * invc * Wl[k * ODIM + c];
    gcat[g * 30 + t] = acc;
}

__global__ void final_kernel(const float* __restrict__ gcat, const float* __restrict__ Wf,
                             const float* __restrict__ bf, float* __restrict__ out) {
    int g = blockIdx.x * blockDim.x + threadIdx.x;
    if (g >= NG) return;
    float z[ODIM];
    float m = -1e30f;
    for (int c = 0; c < ODIM; ++c) {
        float acc = bf[c];
        for (int k = 0; k < 30; ++k) acc += gcat[g * 30 + k] * Wf[k * ODIM + c];
        z[c] = acc;
        m = fmaxf(m, acc);
    }
    float s = 0.0f;
    for (int c = 0; c < ODIM; ++c) { z[c] = expf(z[c] - m); s += z[c]; }
    float inv = 1.0f / s;
    for (int c = 0; c < ODIM; ++c) out[g * ODIM + c] = z[c] * inv;
}

extern "C" void kernel_launch(void* const* d_in, const int* in_sizes, int n_in,
                              void* d_out, int out_size, void* d_ws, size_t ws_size,
                              hipStream_t stream) {
    const float* features = (const float*)d_in[0];
    const int*   edge     = (const int*)d_in[1];
    const int*   batch    = (const int*)d_in[2];
    const float* W1 = (const float*)d_in[3];
    const float* b1 = (const float*)d_in[4];
    const float* W2 = (const float*)d_in[5];
    const float* b2 = (const float*)d_in[6];
    const float* W3 = (const float*)d_in[7];
    const float* b3 = (const float*)d_in[8];
    const float* Wl1 = (const float*)d_in[9];
    const float* bl1 = (const float*)d_in[10];
    const float* Wl2 = (const float*)d_in[11];
    const float* bl2 = (const float*)d_in[12];
    const float* Wl3 = (const float*)d_in[13];
    const float* bl3 = (const float*)d_in[14];
    const float* Wf = (const float*)d_in[15];
    const float* bf = (const float*)d_in[16];

    const int* src = edge;
    const int* dst = edge + N_EDGES;

    // ---- workspace layout (256B-aligned slabs) ----
    char* p = (char*)d_ws;
    auto alloc = [&](size_t bytes) -> char* {
        char* q = p;
        p += (bytes + 255) & ~(size_t)255;
        return q;
    };
    int*      deg   = (int*)alloc(N_NODES * 4);
    float*    sums  = (float*)alloc(3 * NG * F * 4);
    float*    cnt   = (float*)alloc(NG * 4);
    float*    dinv  = (float*)alloc(N_NODES * 4);
    int*      rp    = (int*)alloc((N_NODES + 1) * 4);
    int*      cursor= (int*)alloc(N_NODES * 4);
    int*      bsum  = (int*)alloc(512 * 4);
    float*    gcat  = (float*)alloc(NG * 30 * 4);
    ushort_t* X     = (ushort_t*)alloc((size_t)N_NODES * F * 2);
    ushort_t* H     = (ushort_t*)alloc((size_t)N_NODES * F * 2);
    int2*     meta  = (int2*)alloc((size_t)N_EDGES * 8);
    ushort_t* Wp1   = (ushort_t*)alloc(INDIM * 64 * 2);
    ushort_t* Wp2   = (ushort_t*)alloc(F * 64 * 2);
    ushort_t* Wp3   = (ushort_t*)alloc(F * 64 * 2);

    // zero [deg | sums] (contiguous slabs)
    const int zeroN = (int)(((char*)(sums + 3 * NG * F) - (char*)deg) / 4);
    hipLaunchKernelGGL(zero_kernel, dim3((zeroN + 255) / 256), dim3(256), 0, stream, (float*)deg, zeroN);
    hipLaunchKernelGGL(deg_kernel, dim3((N_EDGES + 255) / 256), dim3(256), 0, stream, dst, deg);
    hipLaunchKernelGGL(dinv_kernel, dim3((N_NODES + 255) / 256), dim3(256), 0, stream, deg, dinv);
    hipLaunchKernelGGL(cnt_bs_kernel, dim3((NG + 255) / 256), dim3(256), 0, stream, batch, cnt);
    hipLaunchKernelGGL(scan1_kernel, dim3(NB_SCAN), dim3(256), 0, stream, deg, rp, bsum);
    hipLaunchKernelGGL(scan2_kernel, dim3(1), dim3(512), 0, stream, bsum);
    hipLaunchKernelGGL(scan3_kernel, dim3(NB_SCAN), dim3(256), 0, stream, rp, bsum, cursor);
    hipLaunchKernelGGL(bin_part_kernel, dim3(BIN_BLOCKS), dim3(256), 0, stream, src, dst, dinv, cursor, meta);

    // W packs
    hipLaunchKernelGGL((packW_kernel<INDIM>), dim3((INDIM * 64 + 255) / 256), dim3(256), 0, stream, W1, Wp1);
    hipLaunchKernelGGL((packW_kernel<F>), dim3((F * 64 + 255) / 256), dim3(256), 0, stream, W2, Wp2);
    hipLaunchKernelGGL((packW_kernel<F>), dim3((F * 64 + 255) / 256), dim3(256), 0, stream, W3, Wp3);

    const int nodeBlocks = N_NODES / 4;          // 25000 (aggregate)
    const int gemmBlocks = (N_NODES + 63) / 64;  // 1563

    // ---- layer 1 (fp32 A read + in-register bf16 convert) ----
    hipLaunchKernelGGL((gemm_mfma_kernel<INDIM, true>), dim3(gemmBlocks), dim3(256), 0, stream, (const void*)features, Wp1, H);
    hipLaunchKernelGGL(aggregate_kernel, dim3(nodeBlocks), dim3(256), 0, stream, H, meta, rp, dinv, b1, batch, X, sums + 0 * NG * F);
    // ---- layer 2 ----
    hipLaunchKernelGGL((gemm_mfma_kernel<F, false>), dim3(gemmBlocks), dim3(256), 0, stream, (const void*)X, Wp2, H);
    hipLaunchKernelGGL(aggregate_kernel, dim3(nodeBlocks), dim3(256), 0, stream, H, meta, rp, dinv, b2, batch, X, sums + 1 * NG * F);
    // ---- layer 3 (no X store needed; pool only) ----
    hipLaunchKernelGGL((gemm_mfma_kernel<F, false>), dim3(gemmBlocks), dim3(256), 0, stream, (const void*)X, Wp3, H);
    hipLaunchKernelGGL(aggregate_kernel, dim3(nodeBlocks), dim3(256), 0, stream, H, meta, rp, dinv, b3, batch, (ushort_t*)nullptr, sums + 2 * NG * F);

    // ---- heads + final ----
    hipLaunchKernelGGL(head_kernel, dim3(NG), dim3(32), 0, stream, sums, cnt,
                       Wl1, bl1, Wl2, bl2, Wl3, bl3, gcat);
    hipLaunchKernelGGL(final_kernel, dim3((NG + 255) / 256), dim3(256), 0, stream, gcat, Wf, bf, (float*)d_out);
}